// Round 11
// baseline (1550.749 us; speedup 1.0000x reference)
//
#include <hip/hip_runtime.h>
#include <math.h>

// ---------------------------------------------------------------------------
// SENSE CG reconstruction, B=1, S=4, C=16, H=W=320, rho=0.1, 15 CG iters.
// R6: FFT-320 = Stockham {5,8,8}; R7: packed-fp32 complex math (v2f);
// R8: K/sP in fp16; R9: passB 16-col tiles, h8v (16B/lane) global access.
// R12: row kernels 512thr/8-wave; R14: Parseval pAp in passB (alpha known
//     before passC2) - verified. R13/R15 (REVERTED): fused update attempts.
// R16: passB-only twiddle-power hoisting (w40^q, w320^q once per thread);
//     removes 6-deep serial cmulf chains from the 4 chained stages.
//     (3rd submission: rounds 9-10 failed on container infra, no data.
//      If this fails again, next round bisects with R14 source.)
// ---------------------------------------------------------------------------

#define NDIM 320
#define HHALF 160
#define HW (NDIM*NDIM)
#define NS 4
#define NC 16
#define RHO_ 0.1f
#define CG_ITERS 15

typedef float v2f __attribute__((ext_vector_type(2)));
typedef _Float16 h2 __attribute__((ext_vector_type(2)));
typedef _Float16 h8v __attribute__((ext_vector_type(8)));

__device__ __forceinline__ v2f h2f(h2 h){ return (v2f){(float)h.x, (float)h.y}; }
__device__ __forceinline__ h2 f2h(v2f v){ return (h2){(_Float16)v.x, (_Float16)v.y}; }

__device__ __forceinline__ void wsync(){
    __builtin_amdgcn_fence(__ATOMIC_ACQ_REL, "wavefront");
    __builtin_amdgcn_wave_barrier();
}

__device__ __forceinline__ float wred(float v){
    #pragma unroll
    for (int o=32;o>0;o>>=1) v += __shfl_down(v,o,64);
    return v;  // valid on lane 0
}

// complex mul: 2 packed FMAs
__device__ __forceinline__ v2f cmulf(v2f a, v2f b){
    return (v2f){a.x,a.x}*b + (v2f){-a.y,a.y}*(v2f){b.y,b.x};
}

template<int SIGMA>
__device__ __forceinline__ v2f cmulw(v2f a, v2f w){
    v2f wb = (SIGMA<0) ? w : (v2f){w.x, -w.y};
    return cmulf(a, wb);
}

template<int SIGMA>
__device__ __forceinline__ v2f mulj(v2f z){  // SIGMA*i*z
    return (v2f){ -(float)SIGMA*z.y, (float)SIGMA*z.x };
}

template<int SIGMA>
__device__ __forceinline__ void radix5(const v2f* u, v2f* v){
    const float C1 = 0.30901699437494742f, S1 = 0.95105651629515357f;
    const float C2 = -0.80901699437494745f, S2 = 0.58778525229247312f;
    v2f t1=u[1]+u[4], t2=u[2]+u[3], t3=u[1]-u[4], t4=u[2]-u[3];
    v[0] = u[0] + t1 + t2;
    v2f m1 = u[0] + t1*C1 + t2*C2;
    v2f m2 = u[0] + t1*C2 + t2*C1;
    v2f n1 = t3*S1 + t4*S2;
    v2f n2 = t3*S2 - t4*S1;
    v2f j1 = mulj<SIGMA>(n1), j2 = mulj<SIGMA>(n2);
    v[1]=m1+j1; v[4]=m1-j1; v[2]=m2+j2; v[3]=m2-j2;
}

template<int SIGMA>
__device__ __forceinline__ void dft8(const v2f* u, v2f* y){
    const float C = 0.70710678118654752f;
    v2f a0=u[0]+u[4], a1=u[0]-u[4];
    v2f a2=u[2]+u[6], a3=u[2]-u[6];
    v2f a4=u[1]+u[5], a5=u[1]-u[5];
    v2f a6=u[3]+u[7], a7=u[3]-u[7];
    v2f j3 = mulj<SIGMA>(a3);
    v2f E0=a0+a2, E2=a0-a2;
    v2f E1=a1+j3, E3=a1-j3;
    v2f j7 = mulj<SIGMA>(a7);
    v2f O0=a4+a6, O2=a4-a6;
    v2f O1=a5+j7, O3=a5-j7;
    v2f W1 = (O1 + mulj<SIGMA>(O1)) * C;
    v2f jO2 = mulj<SIGMA>(O2);
    v2f W3 = (mulj<SIGMA>(O3) - O3) * C;
    y[0]=E0+O0; y[4]=E0-O0;
    y[1]=E1+W1; y[5]=E1-W1;
    y[2]=E2+jO2; y[6]=E2-jO2;
    y[3]=E3+W3; y[7]=E3-W3;
}

// ---- forward Stockham {5,8,8}: natural in -> natural out -------------------
template<int SIGMA>
__device__ __forceinline__ void s1_from_regs(v2f* __restrict__ A, int t,
                                             const v2f* u5){
    v2f v[5];
    radix5<SIGMA>(u5, v);
    #pragma unroll
    for (int c=0;c<5;++c) A[5*t + c] = v[c];
}

template<int SIGMA>
__device__ __forceinline__ void s1_stage(v2f* __restrict__ A, int t){
    v2f u[5];
    #pragma unroll
    for (int q=0;q<5;++q) u[q] = A[t + 64*q];
    wsync();
    s1_from_regs<SIGMA>(A, t, u);
}

template<int SIGMA>
__device__ __forceinline__ void s2_stage(v2f* __restrict__ A, int t, v2f w40){
    if (t < 40){
        v2f u[8];
        #pragma unroll
        for (int q=0;q<8;++q) u[q] = A[t + 40*q];
        wsync();
        v2f wc = w40;
        u[1] = cmulw<SIGMA>(u[1], wc);
        #pragma unroll
        for (int q=2;q<8;++q){ wc = cmulf(wc, w40); u[q] = cmulw<SIGMA>(u[q], wc); }
        v2f v[8];
        dft8<SIGMA>(u, v);
        int k = t % 5, jb = t / 5;
        int base = jb*40 + k;
        #pragma unroll
        for (int c=0;c<8;++c) A[base + 5*c] = v[c];
    }
}

// s2 with precomputed w40 powers (wp[q-1] = w40^q)
template<int SIGMA>
__device__ __forceinline__ void s2_stage_p(v2f* __restrict__ A, int t,
                                           const v2f* wp){
    if (t < 40){
        v2f u[8];
        #pragma unroll
        for (int q=0;q<8;++q) u[q] = A[t + 40*q];
        wsync();
        #pragma unroll
        for (int q=1;q<8;++q) u[q] = cmulw<SIGMA>(u[q], wp[q-1]);
        v2f v[8];
        dft8<SIGMA>(u, v);
        int k = t % 5, jb = t / 5;
        int base = jb*40 + k;
        #pragma unroll
        for (int c=0;c<8;++c) A[base + 5*c] = v[c];
    }
}

template<int SIGMA>
__device__ __forceinline__ void s3_toregs(const v2f* __restrict__ A, int t,
                                          v2f w320, v2f* v){
    if (t < 40){
        v2f u[8];
        #pragma unroll
        for (int q=0;q<8;++q) u[q] = A[t + 40*q];
        v2f wc = w320;
        u[1] = cmulw<SIGMA>(u[1], wc);
        #pragma unroll
        for (int q=2;q<8;++q){ wc = cmulf(wc, w320); u[q] = cmulw<SIGMA>(u[q], wc); }
        dft8<SIGMA>(u, v);
    }
}

// s3 with precomputed w320 powers
template<int SIGMA>
__device__ __forceinline__ void s3_toregs_p(const v2f* __restrict__ A, int t,
                                            const v2f* wp, v2f* v){
    if (t < 40){
        v2f u[8];
        #pragma unroll
        for (int q=0;q<8;++q) u[q] = A[t + 40*q];
        #pragma unroll
        for (int q=1;q<8;++q) u[q] = cmulw<SIGMA>(u[q], wp[q-1]);
        dft8<SIGMA>(u, v);
    }
}

// ---- adjoint network (unnormalized inverse) -------------------------------
template<int SIGMA>
__device__ __forceinline__ void a3_fromregs(v2f* __restrict__ A, int t,
                                            v2f w320, const v2f* vin){
    if (t < 40){
        v2f u[8];
        dft8<SIGMA>(vin, u);
        v2f wc = w320;
        u[1] = cmulw<SIGMA>(u[1], wc);
        #pragma unroll
        for (int q=2;q<8;++q){ wc = cmulf(wc, w320); u[q] = cmulw<SIGMA>(u[q], wc); }
        #pragma unroll
        for (int q=0;q<8;++q) A[t + 40*q] = u[q];
    }
}

// a3 with precomputed w320 powers
template<int SIGMA>
__device__ __forceinline__ void a3_fromregs_p(v2f* __restrict__ A, int t,
                                              const v2f* wp, const v2f* vin){
    if (t < 40){
        v2f u[8];
        dft8<SIGMA>(vin, u);
        #pragma unroll
        for (int q=1;q<8;++q) u[q] = cmulw<SIGMA>(u[q], wp[q-1]);
        #pragma unroll
        for (int q=0;q<8;++q) A[t + 40*q] = u[q];
    }
}

template<int SIGMA>
__device__ __forceinline__ void a2_stage(v2f* __restrict__ A, int t, v2f w40){
    if (t < 40){
        int k = t % 5, jb = t / 5;
        int base = jb*40 + k;
        v2f v[8];
        #pragma unroll
        for (int c=0;c<8;++c) v[c] = A[base + 5*c];
        wsync();
        v2f u[8];
        dft8<SIGMA>(v, u);
        v2f wc = w40;
        u[1] = cmulw<SIGMA>(u[1], wc);
        #pragma unroll
        for (int q=2;q<8;++q){ wc = cmulf(wc, w40); u[q] = cmulw<SIGMA>(u[q], wc); }
        #pragma unroll
        for (int q=0;q<8;++q) A[t + 40*q] = u[q];
    }
}

// a2 with precomputed w40 powers
template<int SIGMA>
__device__ __forceinline__ void a2_stage_p(v2f* __restrict__ A, int t,
                                           const v2f* wp){
    if (t < 40){
        int k = t % 5, jb = t / 5;
        int base = jb*40 + k;
        v2f v[8];
        #pragma unroll
        for (int c=0;c<8;++c) v[c] = A[base + 5*c];
        wsync();
        v2f u[8];
        dft8<SIGMA>(v, u);
        #pragma unroll
        for (int q=1;q<8;++q) u[q] = cmulw<SIGMA>(u[q], wp[q-1]);
        #pragma unroll
        for (int q=0;q<8;++q) A[t + 40*q] = u[q];
    }
}

template<int SIGMA>
__device__ __forceinline__ void a1_toregs(const v2f* __restrict__ A, int t,
                                          v2f* out5){
    v2f v[5];
    #pragma unroll
    for (int c=0;c<5;++c) v[c] = A[5*t + c];
    radix5<SIGMA>(v, out5);
}

__device__ __forceinline__ void make_w(int t, v2f& w40, v2f& w320){
    float sn, cs;
    const float n2pi = -6.283185307179586f;
    __sincosf(n2pi*(float)(t%5)/40.f, &sn, &cs); w40  = (v2f){cs, sn};
    __sincosf(n2pi*(float)t/320.f,    &sn, &cs); w320 = (v2f){cs, sn};
}

__device__ __forceinline__ int sh160(int i){ return i < HHALF ? i + HHALF : i - HHALF; }

// ---------------------------------------------------------------------------
__global__ void k_prep(const v2f* __restrict__ kin, const float* __restrict__ mask,
                       const v2f* __restrict__ csm, h2* __restrict__ sP,
                       float* __restrict__ mscT, h2* __restrict__ K,
                       float* __restrict__ scal)
{
    int gid = blockIdx.x*blockDim.x + threadIdx.x;
    int gsz = gridDim.x*blockDim.x;
    if (gid < 64) scal[gid] = 0.f;
    for (int i = gid; i < NC*HW; i += gsz){
        int w = i % NDIM; int h = (i/NDIM) % NDIM; int c = i/HW;
        sP[i] = f2h(csm[(c*NDIM + sh160(h))*NDIM + sh160(w)]);
    }
    for (int i = gid; i < NS*HW; i += gsz){
        int h = i % NDIM; int wc = (i/NDIM)%NDIM; int s = i/HW;
        float m = mask[(s*NDIM + sh160(h))*NDIM + sh160(wc)];
        mscT[i] = m*m*(1.0f/102400.0f);
    }
    for (int i = gid; i < NS*NC*HW; i += gsz){
        int w = i % NDIM; int h = (i/NDIM)%NDIM; int sc = i/HW;
        int s = sc >> 4;
        int hs = sh160(h), ws = sh160(w);
        float m = mask[(s*NDIM + hs)*NDIM + ws];
        v2f kv = kin[((long)sc*NDIM + hs)*NDIM + ws];
        float f = m*(1.0f/320.0f);
        K[i] = f2h(kv * f);
    }
}

// ---------------------------------------------------------------------------
// PassA (R12): p = r + beta*p fused; K[s,c,h,:] = rowFFT(s'_c .* p).
// grid = S*80*4 ; 512 thr = 8 waves: waves 0-3 rows x coils {c,c+1},
// waves 4-7 same rows x coils {c+2,c+3}. pv staged via LDS (half0 loads).
__global__ __launch_bounds__(512) void k_passA(
    const v2f* __restrict__ rv_, const v2f* __restrict__ pOld,
    v2f* __restrict__ pNew, const h2* __restrict__ sP,
    h2* __restrict__ K, float* __restrict__ scal, int iter)
{
    int bid = blockIdx.x;
    int cg = bid & 3;
    int hg = (bid>>2) % 80;
    int s  = bid / (4*80);
    int tid = threadIdx.x;
    int wv = tid>>6; int rl = wv&3; int half = wv>>2; int t = tid&63;
    int h = hg*4 + rl;
    __shared__ v2f bufA[8][NDIM];
    __shared__ v2f pbuf[4][NDIM];
    v2f* A = &bufA[wv][0];
    v2f w40, w320; make_w(t, w40, w320);
    long base = (long)s*HW + h*NDIM;
    v2f pv[5];
    if (half == 0){
        float beta = 0.f;
        if (iter > 0) beta = scal[iter] / (scal[iter-1] + 1e-12f);
        #pragma unroll
        for (int j=0;j<5;++j){
            int idx = t + 64*j;
            v2f rr = rv_[base+idx];
            if (iter > 0){
                v2f pp = pOld[base+idx];
                pv[j] = rr + pp*beta;
            } else pv[j] = rr;
            pbuf[rl][idx] = pv[j];
        }
        if (cg == 0){
            float d = 0.f;
            #pragma unroll
            for (int j=0;j<5;++j){
                pNew[base + t + 64*j] = pv[j];
                d += pv[j].x*pv[j].x + pv[j].y*pv[j].y;
            }
            float wd = wred(d);
            if (t==0) atomicAdd(&scal[16+iter], RHO_*wd);
        }
    }
    __syncthreads();
    if (half == 1){
        #pragma unroll
        for (int j=0;j<5;++j) pv[j] = pbuf[rl][t + 64*j];
    }
    int c = cg*4 + half*2;
    const h2* srow = sP + (long)c*HW + h*NDIM;
    v2f sv[5];
    #pragma unroll
    for (int j=0;j<5;++j) sv[j] = h2f(srow[t+64*j]);
    #pragma unroll
    for (int c0=0;c0<2;++c0){
        v2f u5[5];
        #pragma unroll
        for (int j=0;j<5;++j) u5[j] = cmulf(sv[j], pv[j]);
        v2f sv2[5];
        if (c0<1){
            const h2* sr2 = srow + (long)HW;
            #pragma unroll
            for (int j=0;j<5;++j) sv2[j] = h2f(sr2[t+64*j]);
        }
        wsync();                                   // prior-iter S3 reads done
        s1_from_regs<-1>(A, t, u5);
        wsync();
        s2_stage<-1>(A, t, w40);
        wsync();
        v2f v8[8];
        s3_toregs<-1>(A, t, w320, v8);
        long kb = ((long)(s*NC + c + c0))*HW + h*NDIM;
        if (t < 40){
            #pragma unroll
            for (int cc=0;cc<8;++cc) K[kb + t + 40*cc] = f2h(v8[cc]);
        }
        if (c0<1){
            #pragma unroll
            for (int j=0;j<5;++j) sv[j]=sv2[j];
        }
    }
}

// ---------------------------------------------------------------------------
// PassB (R9 structure + Parseval pAp + R16 twiddle hoist): 16-column LDS
// tile; h8v (16B/lane). Twiddle powers w40^q, w320^q precomputed once per
// thread -> serial per-stage chains removed. One pap atomic per block.
__global__ __launch_bounds__(1024) void k_passB(h2* __restrict__ K,
    const float* __restrict__ mscT, float* __restrict__ scal, int iter,
    int doMask)
{
    constexpr int L = 324;
    int bid = blockIdx.x;
    int wt = bid % 20;
    int sc = bid / 20;
    int s = sc >> 4;
    int tid = threadIdx.x;
    int col = tid >> 6;          // 0..15
    int t = tid & 63;
    int w0 = wt*16;
    __shared__ v2f bufA[16][L];
    __shared__ float redP[16];
    v2f w40, w320; make_w(t, w40, w320);
    v2f w40p[7], w320p[7];
    {
        v2f wc = w40;  w40p[0] = wc;
        #pragma unroll
        for (int q=2;q<8;++q){ wc = cmulf(wc, w40);  w40p[q-1] = wc; }
        v2f wd = w320; w320p[0] = wd;
        #pragma unroll
        for (int q=2;q<8;++q){ wd = cmulf(wd, w320); w320p[q-1] = wd; }
    }
    float mv[8];
    if (doMask && t < 40){
        const float* mcol = mscT + (long)s*HW + (long)(w0+col)*NDIM;
        #pragma unroll
        for (int cc=0;cc<8;++cc) mv[cc] = mcol[t+40*cc];
    }
    long gb = (long)sc*HW + w0;
    for (int i = tid; i < NDIM*4; i += 1024){
        int row = i >> 2, ch = i & 3;
        h8v val = *(const h8v*)&K[gb + (long)row*NDIM + ch*4];
        #pragma unroll
        for (int k=0;k<4;++k)
            bufA[ch*4+k][row] = (v2f){(float)val[2*k], (float)val[2*k+1]};
    }
    __syncthreads();
    v2f* A = &bufA[col][0];
    if (doMask){
        s1_stage<-1>(A, t);
        wsync();
        s2_stage_p<-1>(A, t, w40p);
        wsync();
        v2f v8[8];
        s3_toregs_p<-1>(A, t, w320p, v8);
        float pap = 0.f;
        if (t < 40){
            #pragma unroll
            for (int cc=0;cc<8;++cc){
                float m = mv[cc];
                pap += m*(v8[cc].x*v8[cc].x + v8[cc].y*v8[cc].y);
                v8[cc] = v8[cc]*m;
            }
        }
        {
            float wp = wred(pap);
            if (t==0) redP[col] = wp;
        }
        wsync();
        a3_fromregs_p<1>(A, t, w320p, v8);
        wsync();
        a2_stage_p<1>(A, t, w40p);
        wsync();
        v2f x5[5];
        a1_toregs<1>(A, t, x5);
        wsync();
        #pragma unroll
        for (int q=0;q<5;++q) A[t + 64*q] = x5[q];
    } else {
        s1_stage<1>(A, t);
        wsync();
        s2_stage_p<1>(A, t, w40p);
        wsync();
        v2f v8[8];
        s3_toregs_p<1>(A, t, w320p, v8);
        wsync();
        if (t < 40){
            #pragma unroll
            for (int cc=0;cc<8;++cc) A[t + 40*cc] = v8[cc];
        }
    }
    __syncthreads();
    for (int i = tid; i < NDIM*4; i += 1024){
        int row = i >> 2, ch = i & 3;
        h8v val;
        #pragma unroll
        for (int k=0;k<4;++k){
            v2f u = bufA[ch*4+k][row];
            val[2*k] = (_Float16)u.x; val[2*k+1] = (_Float16)u.y;
        }
        *(h8v*)&K[gb + (long)row*NDIM + ch*4] = val;
    }
    if (doMask && tid==0){
        float sum = 0.f;
        #pragma unroll
        for (int k=0;k<16;++k) sum += redP[k];
        atomicAdd(&scal[16+iter], sum);
    }
}

// ---------------------------------------------------------------------------
// PassC2 (R12 FFT structure, dot work removed): row inverse of 4 coils
// (2 per wave-half), halves combined via LDS; conj(s')-combine into part[cg].
// grid = S*80*4 ; 512 thr = 8 waves.
__global__ __launch_bounds__(512) void k_passC2(
    const h2* __restrict__ K, const h2* __restrict__ sP,
    v2f* __restrict__ part)
{
    int bid = blockIdx.x;
    int cg = bid & 3;
    int hg = (bid>>2) % 80;
    int s  = bid / (4*80);
    int tid = threadIdx.x;
    int wv = tid>>6; int rl = wv&3; int half = wv>>2; int t = tid&63;
    int h = hg*4 + rl;
    __shared__ v2f bufA[8][NDIM];
    v2f* A = &bufA[wv][0];
    v2f w40, w320; make_w(t, w40, w320);
    int c = cg*4 + half*2;
    long kb0 = ((long)(s*NC + c))*HW + h*NDIM;
    const h2* srow = sP + (long)c*HW + h*NDIM;
    v2f kv[8], sv[5];
    if (t < 40){
        #pragma unroll
        for (int cc=0;cc<8;++cc) kv[cc] = h2f(K[kb0 + t + 40*cc]);
    }
    #pragma unroll
    for (int j=0;j<5;++j) sv[j] = h2f(srow[t+64*j]);
    v2f acc[5];
    #pragma unroll
    for (int j=0;j<5;++j) acc[j]=(v2f){0.f,0.f};
    #pragma unroll
    for (int c0=0;c0<2;++c0){
        a3_fromregs<1>(A, t, w320, kv);
        v2f kv2[8], sv2[5];
        if (c0<1){
            long kb = kb0 + (long)HW;
            const h2* sr2 = srow + (long)HW;
            if (t < 40){
                #pragma unroll
                for (int cc=0;cc<8;++cc) kv2[cc] = h2f(K[kb + t + 40*cc]);
            }
            #pragma unroll
            for (int j=0;j<5;++j) sv2[j] = h2f(sr2[t+64*j]);
        }
        wsync();
        a2_stage<1>(A, t, w40);
        wsync();
        v2f x5[5];
        a1_toregs<1>(A, t, x5);
        #pragma unroll
        for (int j=0;j<5;++j){
            // acc += conj(s)*u  (2 packed FMAs)
            acc[j] += (v2f){sv[j].x,sv[j].x}*x5[j]
                    + (v2f){sv[j].y,-sv[j].y}*(v2f){x5[j].y,x5[j].x};
        }
        wsync();                   // a1 reads done before next a3 writes
        if (c0<1){
            #pragma unroll
            for (int cc=0;cc<8;++cc) kv[cc]=kv2[cc];
            #pragma unroll
            for (int j=0;j<5;++j) sv[j]=sv2[j];
        }
    }
    // combine halves: half1 deposits acc in its own LDS row buffer
    if (half == 1){
        #pragma unroll
        for (int j=0;j<5;++j) A[t + 64*j] = acc[j];
    }
    __syncthreads();
    if (half == 0){
        long obase = ((long)cg*NS + s)*HW + h*NDIM;
        #pragma unroll
        for (int j=0;j<5;++j){
            int idx = t + 64*j;
            part[obase+idx] = acc[j] + bufA[4+rl][idx];
        }
    }
}

// ---------------------------------------------------------------------------
__global__ __launch_bounds__(256) void k_rhs_fin(
    const v2f* __restrict__ part, const v2f* __restrict__ Iin,
    v2f* __restrict__ r, v2f* __restrict__ x, float* __restrict__ scal)
{
    __shared__ float red[256];
    int gid = blockIdx.x*blockDim.x + threadIdx.x;
    int gsz = gridDim.x*blockDim.x;
    float rs = 0.f;
    const int NV = NS*HW;
    for (int i = gid; i < NV; i += gsz){
        int w = i % NDIM; int h = (i/NDIM)%NDIM; int s = i/HW;
        v2f iv = Iin[((long)s*NDIM + sh160(h))*NDIM + sh160(w)];
        v2f rr = part[i] + part[NV+i] + part[2*NV+i] + part[3*NV+i] + iv*RHO_;
        r[i] = rr;
        x[i] = (v2f){0.f,0.f};
        rs += rr.x*rr.x + rr.y*rr.y;
    }
    red[threadIdx.x]=rs; __syncthreads();
    for (int o=128;o>0;o>>=1){ if (threadIdx.x<o) red[threadIdx.x]+=red[threadIdx.x+o]; __syncthreads(); }
    if (threadIdx.x==0) atomicAdd(&scal[0], red[0]);
}

// ---------------------------------------------------------------------------
__global__ __launch_bounds__(256) void k_update(
    v2f* __restrict__ x, v2f* __restrict__ r,
    const v2f* __restrict__ p, const v2f* __restrict__ part,
    float* __restrict__ scal, int iter)
{
    __shared__ float red[256];
    float alpha = scal[iter] / (scal[16+iter] + 1e-12f);
    int gid = blockIdx.x*blockDim.x + threadIdx.x;
    int gsz = gridDim.x*blockDim.x;
    float rs = 0.f;
    const int NV = NS*HW;
    for (int i = gid; i < NV; i += gsz){
        v2f pvv=p[i];
        v2f av = part[i] + part[NV+i] + part[2*NV+i] + part[3*NV+i] + pvv*RHO_;
        v2f xv = x[i] + pvv*alpha;
        v2f rv = r[i] - av*alpha;
        x[i]=xv; r[i]=rv;
        rs += rv.x*rv.x + rv.y*rv.y;
    }
    red[threadIdx.x]=rs; __syncthreads();
    for (int o=128;o>0;o>>=1){ if (threadIdx.x<o) red[threadIdx.x]+=red[threadIdx.x+o]; __syncthreads(); }
    if (threadIdx.x==0) atomicAdd(&scal[iter+1], red[0]);
}

__global__ void k_final(const v2f* __restrict__ x, v2f* __restrict__ out)
{
    int gid = blockIdx.x*blockDim.x + threadIdx.x;
    int gsz = gridDim.x*blockDim.x;
    for (int i = gid; i < NS*HW; i += gsz){
        int w = i % NDIM; int h = (i/NDIM)%NDIM; int s = i/HW;
        out[i] = x[(long)s*HW + sh160(h)*NDIM + sh160(w)];
    }
}

extern "C" void kernel_launch(void* const* d_in, const int* in_sizes, int n_in,
                              void* d_out, int out_size, void* d_ws, size_t ws_size,
                              hipStream_t stream) {
    (void)in_sizes; (void)n_in; (void)out_size; (void)ws_size;
    const v2f* kin  = (const v2f*)d_in[0];
    const v2f* Iin  = (const v2f*)d_in[1];
    const v2f* csm  = (const v2f*)d_in[2];
    const float* mask = (const float*)d_in[3];

    char* w = (char*)d_ws;
    size_t off = 0;
    float* scal = (float*)(w+off);  off += 1024;
    h2* sP    = (h2*)(w+off);  off += (size_t)NC*HW*4;
    float* mscT = (float*)(w+off); off += (size_t)NS*HW*4;
    h2* K     = (h2*)(w+off);  off += (size_t)NS*NC*HW*4;
    v2f* x    = (v2f*)(w+off); off += (size_t)NS*HW*8;
    v2f* r    = (v2f*)(w+off); off += (size_t)NS*HW*8;
    v2f* pA   = (v2f*)(w+off); off += (size_t)NS*HW*8;
    v2f* pB   = (v2f*)(w+off); off += (size_t)NS*HW*8;
    v2f* part = (v2f*)(w+off); off += (size_t)4*NS*HW*8;

    k_prep<<<2048,256,0,stream>>>(kin, mask, csm, sP, mscT, K, scal);
    k_passB<<<NS*NC*20,1024,0,stream>>>(K, mscT, scal, 0, 0);
    k_passC2<<<NS*80*4,512,0,stream>>>(K, sP, part);
    k_rhs_fin<<<640,256,0,stream>>>(part, Iin, r, x, scal);

    for (int it=0; it<CG_ITERS; ++it){
        v2f* pNew = (it&1)? pB : pA;
        v2f* pOld = (it&1)? pA : pB;
        k_passA<<<NS*80*4,512,0,stream>>>(r, pOld, pNew, sP, K, scal, it);
        k_passB<<<NS*NC*20,1024,0,stream>>>(K, mscT, scal, it, 1);
        k_passC2<<<NS*80*4,512,0,stream>>>(K, sP, part);
        k_update<<<640,256,0,stream>>>(x, r, pNew, part, scal, it);
    }
    k_final<<<512,256,0,stream>>>(x, (v2f*)d_out);
}

// Round 12
// 1442.916 us; speedup vs baseline: 1.0747x; 1.0747x over previous
//
#include <hip/hip_runtime.h>
#include <math.h>

// ---------------------------------------------------------------------------
// SENSE CG reconstruction, B=1, S=4, C=16, H=W=320, rho=0.1, 15 CG iters.
// R6: FFT-320 = Stockham {5,8,8}; R7: packed-fp32 complex math (v2f);
// R8: K/sP in fp16; R9: passB 16-col tiles, h8v (16B/lane) global access.
// R12: row kernels 512thr/8-wave; R14: Parseval pAp in passB. VERIFIED 1459.
// R13/R15 (REVERTED): fused-update attempts. R16 (REVERTED): twiddle hoist
//     regressed 1459->1550 (VGPR unchanged at 36; codegen perturbed).
// R17: R14 base + passB LDS pad L 324->325. R16's counters: passB
//     SQ_LDS_BANK_CONFLICT=2.09M. Column stride 648 dw = 8 mod 32 makes the
//     transpose loops an exact 4-way conflict (same row, 4 ch values ->
//     same bank). Stride 650 dw = 10 mod 32 -> worst 2-way (free, m136).
//     FFT stages are within-column: unaffected.
// ---------------------------------------------------------------------------

#define NDIM 320
#define HHALF 160
#define HW (NDIM*NDIM)
#define NS 4
#define NC 16
#define RHO_ 0.1f
#define CG_ITERS 15

typedef float v2f __attribute__((ext_vector_type(2)));
typedef _Float16 h2 __attribute__((ext_vector_type(2)));
typedef _Float16 h8v __attribute__((ext_vector_type(8)));

__device__ __forceinline__ v2f h2f(h2 h){ return (v2f){(float)h.x, (float)h.y}; }
__device__ __forceinline__ h2 f2h(v2f v){ return (h2){(_Float16)v.x, (_Float16)v.y}; }

__device__ __forceinline__ void wsync(){
    __builtin_amdgcn_fence(__ATOMIC_ACQ_REL, "wavefront");
    __builtin_amdgcn_wave_barrier();
}

__device__ __forceinline__ float wred(float v){
    #pragma unroll
    for (int o=32;o>0;o>>=1) v += __shfl_down(v,o,64);
    return v;  // valid on lane 0
}

// complex mul: 2 packed FMAs
__device__ __forceinline__ v2f cmulf(v2f a, v2f b){
    return (v2f){a.x,a.x}*b + (v2f){-a.y,a.y}*(v2f){b.y,b.x};
}

template<int SIGMA>
__device__ __forceinline__ v2f cmulw(v2f a, v2f w){
    v2f wb = (SIGMA<0) ? w : (v2f){w.x, -w.y};
    return cmulf(a, wb);
}

template<int SIGMA>
__device__ __forceinline__ v2f mulj(v2f z){  // SIGMA*i*z
    return (v2f){ -(float)SIGMA*z.y, (float)SIGMA*z.x };
}

template<int SIGMA>
__device__ __forceinline__ void radix5(const v2f* u, v2f* v){
    const float C1 = 0.30901699437494742f, S1 = 0.95105651629515357f;
    const float C2 = -0.80901699437494745f, S2 = 0.58778525229247312f;
    v2f t1=u[1]+u[4], t2=u[2]+u[3], t3=u[1]-u[4], t4=u[2]-u[3];
    v[0] = u[0] + t1 + t2;
    v2f m1 = u[0] + t1*C1 + t2*C2;
    v2f m2 = u[0] + t1*C2 + t2*C1;
    v2f n1 = t3*S1 + t4*S2;
    v2f n2 = t3*S2 - t4*S1;
    v2f j1 = mulj<SIGMA>(n1), j2 = mulj<SIGMA>(n2);
    v[1]=m1+j1; v[4]=m1-j1; v[2]=m2+j2; v[3]=m2-j2;
}

template<int SIGMA>
__device__ __forceinline__ void dft8(const v2f* u, v2f* y){
    const float C = 0.70710678118654752f;
    v2f a0=u[0]+u[4], a1=u[0]-u[4];
    v2f a2=u[2]+u[6], a3=u[2]-u[6];
    v2f a4=u[1]+u[5], a5=u[1]-u[5];
    v2f a6=u[3]+u[7], a7=u[3]-u[7];
    v2f j3 = mulj<SIGMA>(a3);
    v2f E0=a0+a2, E2=a0-a2;
    v2f E1=a1+j3, E3=a1-j3;
    v2f j7 = mulj<SIGMA>(a7);
    v2f O0=a4+a6, O2=a4-a6;
    v2f O1=a5+j7, O3=a5-j7;
    v2f W1 = (O1 + mulj<SIGMA>(O1)) * C;
    v2f jO2 = mulj<SIGMA>(O2);
    v2f W3 = (mulj<SIGMA>(O3) - O3) * C;
    y[0]=E0+O0; y[4]=E0-O0;
    y[1]=E1+W1; y[5]=E1-W1;
    y[2]=E2+jO2; y[6]=E2-jO2;
    y[3]=E3+W3; y[7]=E3-W3;
}

// ---- forward Stockham {5,8,8}: natural in -> natural out -------------------
template<int SIGMA>
__device__ __forceinline__ void s1_from_regs(v2f* __restrict__ A, int t,
                                             const v2f* u5){
    v2f v[5];
    radix5<SIGMA>(u5, v);
    #pragma unroll
    for (int c=0;c<5;++c) A[5*t + c] = v[c];
}

template<int SIGMA>
__device__ __forceinline__ void s1_stage(v2f* __restrict__ A, int t){
    v2f u[5];
    #pragma unroll
    for (int q=0;q<5;++q) u[q] = A[t + 64*q];
    wsync();
    s1_from_regs<SIGMA>(A, t, u);
}

template<int SIGMA>
__device__ __forceinline__ void s2_stage(v2f* __restrict__ A, int t, v2f w40){
    if (t < 40){
        v2f u[8];
        #pragma unroll
        for (int q=0;q<8;++q) u[q] = A[t + 40*q];
        wsync();
        v2f wc = w40;
        u[1] = cmulw<SIGMA>(u[1], wc);
        #pragma unroll
        for (int q=2;q<8;++q){ wc = cmulf(wc, w40); u[q] = cmulw<SIGMA>(u[q], wc); }
        v2f v[8];
        dft8<SIGMA>(u, v);
        int k = t % 5, jb = t / 5;
        int base = jb*40 + k;
        #pragma unroll
        for (int c=0;c<8;++c) A[base + 5*c] = v[c];
    }
}

template<int SIGMA>
__device__ __forceinline__ void s3_toregs(const v2f* __restrict__ A, int t,
                                          v2f w320, v2f* v){
    if (t < 40){
        v2f u[8];
        #pragma unroll
        for (int q=0;q<8;++q) u[q] = A[t + 40*q];
        v2f wc = w320;
        u[1] = cmulw<SIGMA>(u[1], wc);
        #pragma unroll
        for (int q=2;q<8;++q){ wc = cmulf(wc, w320); u[q] = cmulw<SIGMA>(u[q], wc); }
        dft8<SIGMA>(u, v);
    }
}

// ---- adjoint network (unnormalized inverse) -------------------------------
template<int SIGMA>
__device__ __forceinline__ void a3_fromregs(v2f* __restrict__ A, int t,
                                            v2f w320, const v2f* vin){
    if (t < 40){
        v2f u[8];
        dft8<SIGMA>(vin, u);
        v2f wc = w320;
        u[1] = cmulw<SIGMA>(u[1], wc);
        #pragma unroll
        for (int q=2;q<8;++q){ wc = cmulf(wc, w320); u[q] = cmulw<SIGMA>(u[q], wc); }
        #pragma unroll
        for (int q=0;q<8;++q) A[t + 40*q] = u[q];
    }
}

template<int SIGMA>
__device__ __forceinline__ void a2_stage(v2f* __restrict__ A, int t, v2f w40){
    if (t < 40){
        int k = t % 5, jb = t / 5;
        int base = jb*40 + k;
        v2f v[8];
        #pragma unroll
        for (int c=0;c<8;++c) v[c] = A[base + 5*c];
        wsync();
        v2f u[8];
        dft8<SIGMA>(v, u);
        v2f wc = w40;
        u[1] = cmulw<SIGMA>(u[1], wc);
        #pragma unroll
        for (int q=2;q<8;++q){ wc = cmulf(wc, w40); u[q] = cmulw<SIGMA>(u[q], wc); }
        #pragma unroll
        for (int q=0;q<8;++q) A[t + 40*q] = u[q];
    }
}

template<int SIGMA>
__device__ __forceinline__ void a1_toregs(const v2f* __restrict__ A, int t,
                                          v2f* out5){
    v2f v[5];
    #pragma unroll
    for (int c=0;c<5;++c) v[c] = A[5*t + c];
    radix5<SIGMA>(v, out5);
}

__device__ __forceinline__ void make_w(int t, v2f& w40, v2f& w320){
    float sn, cs;
    const float n2pi = -6.283185307179586f;
    __sincosf(n2pi*(float)(t%5)/40.f, &sn, &cs); w40  = (v2f){cs, sn};
    __sincosf(n2pi*(float)t/320.f,    &sn, &cs); w320 = (v2f){cs, sn};
}

__device__ __forceinline__ int sh160(int i){ return i < HHALF ? i + HHALF : i - HHALF; }

// ---------------------------------------------------------------------------
__global__ void k_prep(const v2f* __restrict__ kin, const float* __restrict__ mask,
                       const v2f* __restrict__ csm, h2* __restrict__ sP,
                       float* __restrict__ mscT, h2* __restrict__ K,
                       float* __restrict__ scal)
{
    int gid = blockIdx.x*blockDim.x + threadIdx.x;
    int gsz = gridDim.x*blockDim.x;
    if (gid < 64) scal[gid] = 0.f;
    for (int i = gid; i < NC*HW; i += gsz){
        int w = i % NDIM; int h = (i/NDIM) % NDIM; int c = i/HW;
        sP[i] = f2h(csm[(c*NDIM + sh160(h))*NDIM + sh160(w)]);
    }
    for (int i = gid; i < NS*HW; i += gsz){
        int h = i % NDIM; int wc = (i/NDIM)%NDIM; int s = i/HW;
        float m = mask[(s*NDIM + sh160(h))*NDIM + sh160(wc)];
        mscT[i] = m*m*(1.0f/102400.0f);
    }
    for (int i = gid; i < NS*NC*HW; i += gsz){
        int w = i % NDIM; int h = (i/NDIM)%NDIM; int sc = i/HW;
        int s = sc >> 4;
        int hs = sh160(h), ws = sh160(w);
        float m = mask[(s*NDIM + hs)*NDIM + ws];
        v2f kv = kin[((long)sc*NDIM + hs)*NDIM + ws];
        float f = m*(1.0f/320.0f);
        K[i] = f2h(kv * f);
    }
}

// ---------------------------------------------------------------------------
// PassA (R12): p = r + beta*p fused; K[s,c,h,:] = rowFFT(s'_c .* p).
// grid = S*80*4 ; 512 thr = 8 waves: waves 0-3 rows x coils {c,c+1},
// waves 4-7 same rows x coils {c+2,c+3}. pv staged via LDS (half0 loads).
__global__ __launch_bounds__(512) void k_passA(
    const v2f* __restrict__ rv_, const v2f* __restrict__ pOld,
    v2f* __restrict__ pNew, const h2* __restrict__ sP,
    h2* __restrict__ K, float* __restrict__ scal, int iter)
{
    int bid = blockIdx.x;
    int cg = bid & 3;
    int hg = (bid>>2) % 80;
    int s  = bid / (4*80);
    int tid = threadIdx.x;
    int wv = tid>>6; int rl = wv&3; int half = wv>>2; int t = tid&63;
    int h = hg*4 + rl;
    __shared__ v2f bufA[8][NDIM];
    __shared__ v2f pbuf[4][NDIM];
    v2f* A = &bufA[wv][0];
    v2f w40, w320; make_w(t, w40, w320);
    long base = (long)s*HW + h*NDIM;
    v2f pv[5];
    if (half == 0){
        float beta = 0.f;
        if (iter > 0) beta = scal[iter] / (scal[iter-1] + 1e-12f);
        #pragma unroll
        for (int j=0;j<5;++j){
            int idx = t + 64*j;
            v2f rr = rv_[base+idx];
            if (iter > 0){
                v2f pp = pOld[base+idx];
                pv[j] = rr + pp*beta;
            } else pv[j] = rr;
            pbuf[rl][idx] = pv[j];
        }
        if (cg == 0){
            float d = 0.f;
            #pragma unroll
            for (int j=0;j<5;++j){
                pNew[base + t + 64*j] = pv[j];
                d += pv[j].x*pv[j].x + pv[j].y*pv[j].y;
            }
            float wd = wred(d);
            if (t==0) atomicAdd(&scal[16+iter], RHO_*wd);
        }
    }
    __syncthreads();
    if (half == 1){
        #pragma unroll
        for (int j=0;j<5;++j) pv[j] = pbuf[rl][t + 64*j];
    }
    int c = cg*4 + half*2;
    const h2* srow = sP + (long)c*HW + h*NDIM;
    v2f sv[5];
    #pragma unroll
    for (int j=0;j<5;++j) sv[j] = h2f(srow[t+64*j]);
    #pragma unroll
    for (int c0=0;c0<2;++c0){
        v2f u5[5];
        #pragma unroll
        for (int j=0;j<5;++j) u5[j] = cmulf(sv[j], pv[j]);
        v2f sv2[5];
        if (c0<1){
            const h2* sr2 = srow + (long)HW;
            #pragma unroll
            for (int j=0;j<5;++j) sv2[j] = h2f(sr2[t+64*j]);
        }
        wsync();                                   // prior-iter S3 reads done
        s1_from_regs<-1>(A, t, u5);
        wsync();
        s2_stage<-1>(A, t, w40);
        wsync();
        v2f v8[8];
        s3_toregs<-1>(A, t, w320, v8);
        long kb = ((long)(s*NC + c + c0))*HW + h*NDIM;
        if (t < 40){
            #pragma unroll
            for (int cc=0;cc<8;++cc) K[kb + t + 40*cc] = f2h(v8[cc]);
        }
        if (c0<1){
            #pragma unroll
            for (int j=0;j<5;++j) sv[j]=sv2[j];
        }
    }
}

// ---------------------------------------------------------------------------
// PassB (R9 structure + Parseval pAp, R17 pad): 16-column LDS tile; h8v
// (16B/lane). L=325: col stride 650 dw = 10 mod 32 -> transpose loops max
// 2-way bank aliasing (free) instead of 4-way at L=324.
// colFFT -> [pap += mv*|v8|^2] -> mask -> colIFFT (doMask=1), or
// colFFT<+1> only (doMask=0). One pap atomic per block.
__global__ __launch_bounds__(1024) void k_passB(h2* __restrict__ K,
    const float* __restrict__ mscT, float* __restrict__ scal, int iter,
    int doMask)
{
    constexpr int L = 325;
    int bid = blockIdx.x;
    int wt = bid % 20;
    int sc = bid / 20;
    int s = sc >> 4;
    int tid = threadIdx.x;
    int col = tid >> 6;          // 0..15
    int t = tid & 63;
    int w0 = wt*16;
    __shared__ v2f bufA[16][L];
    __shared__ float redP[16];
    v2f w40, w320; make_w(t, w40, w320);
    float mv[8];
    if (doMask && t < 40){
        const float* mcol = mscT + (long)s*HW + (long)(w0+col)*NDIM;
        #pragma unroll
        for (int cc=0;cc<8;++cc) mv[cc] = mcol[t+40*cc];
    }
    long gb = (long)sc*HW + w0;
    for (int i = tid; i < NDIM*4; i += 1024){
        int row = i >> 2, ch = i & 3;
        h8v val = *(const h8v*)&K[gb + (long)row*NDIM + ch*4];
        #pragma unroll
        for (int k=0;k<4;++k)
            bufA[ch*4+k][row] = (v2f){(float)val[2*k], (float)val[2*k+1]};
    }
    __syncthreads();
    v2f* A = &bufA[col][0];
    if (doMask){
        s1_stage<-1>(A, t);
        wsync();
        s2_stage<-1>(A, t, w40);
        wsync();
        v2f v8[8];
        s3_toregs<-1>(A, t, w320, v8);
        float pap = 0.f;
        if (t < 40){
            #pragma unroll
            for (int cc=0;cc<8;++cc){
                float m = mv[cc];
                pap += m*(v8[cc].x*v8[cc].x + v8[cc].y*v8[cc].y);
                v8[cc] = v8[cc]*m;
            }
        }
        {
            float wp = wred(pap);
            if (t==0) redP[col] = wp;
        }
        wsync();
        a3_fromregs<1>(A, t, w320, v8);
        wsync();
        a2_stage<1>(A, t, w40);
        wsync();
        v2f x5[5];
        a1_toregs<1>(A, t, x5);
        wsync();
        #pragma unroll
        for (int q=0;q<5;++q) A[t + 64*q] = x5[q];
    } else {
        s1_stage<1>(A, t);
        wsync();
        s2_stage<1>(A, t, w40);
        wsync();
        v2f v8[8];
        s3_toregs<1>(A, t, w320, v8);
        wsync();
        if (t < 40){
            #pragma unroll
            for (int cc=0;cc<8;++cc) A[t + 40*cc] = v8[cc];
        }
    }
    __syncthreads();
    for (int i = tid; i < NDIM*4; i += 1024){
        int row = i >> 2, ch = i & 3;
        h8v val;
        #pragma unroll
        for (int k=0;k<4;++k){
            v2f u = bufA[ch*4+k][row];
            val[2*k] = (_Float16)u.x; val[2*k+1] = (_Float16)u.y;
        }
        *(h8v*)&K[gb + (long)row*NDIM + ch*4] = val;
    }
    if (doMask && tid==0){
        float sum = 0.f;
        #pragma unroll
        for (int k=0;k<16;++k) sum += redP[k];
        atomicAdd(&scal[16+iter], sum);
    }
}

// ---------------------------------------------------------------------------
// PassC2 (R12 FFT structure, dot work removed): row inverse of 4 coils
// (2 per wave-half), halves combined via LDS; conj(s')-combine into part[cg].
// grid = S*80*4 ; 512 thr = 8 waves.
__global__ __launch_bounds__(512) void k_passC2(
    const h2* __restrict__ K, const h2* __restrict__ sP,
    v2f* __restrict__ part)
{
    int bid = blockIdx.x;
    int cg = bid & 3;
    int hg = (bid>>2) % 80;
    int s  = bid / (4*80);
    int tid = threadIdx.x;
    int wv = tid>>6; int rl = wv&3; int half = wv>>2; int t = tid&63;
    int h = hg*4 + rl;
    __shared__ v2f bufA[8][NDIM];
    v2f* A = &bufA[wv][0];
    v2f w40, w320; make_w(t, w40, w320);
    int c = cg*4 + half*2;
    long kb0 = ((long)(s*NC + c))*HW + h*NDIM;
    const h2* srow = sP + (long)c*HW + h*NDIM;
    v2f kv[8], sv[5];
    if (t < 40){
        #pragma unroll
        for (int cc=0;cc<8;++cc) kv[cc] = h2f(K[kb0 + t + 40*cc]);
    }
    #pragma unroll
    for (int j=0;j<5;++j) sv[j] = h2f(srow[t+64*j]);
    v2f acc[5];
    #pragma unroll
    for (int j=0;j<5;++j) acc[j]=(v2f){0.f,0.f};
    #pragma unroll
    for (int c0=0;c0<2;++c0){
        a3_fromregs<1>(A, t, w320, kv);
        v2f kv2[8], sv2[5];
        if (c0<1){
            long kb = kb0 + (long)HW;
            const h2* sr2 = srow + (long)HW;
            if (t < 40){
                #pragma unroll
                for (int cc=0;cc<8;++cc) kv2[cc] = h2f(K[kb + t + 40*cc]);
            }
            #pragma unroll
            for (int j=0;j<5;++j) sv2[j] = h2f(sr2[t+64*j]);
        }
        wsync();
        a2_stage<1>(A, t, w40);
        wsync();
        v2f x5[5];
        a1_toregs<1>(A, t, x5);
        #pragma unroll
        for (int j=0;j<5;++j){
            // acc += conj(s)*u  (2 packed FMAs)
            acc[j] += (v2f){sv[j].x,sv[j].x}*x5[j]
                    + (v2f){sv[j].y,-sv[j].y}*(v2f){x5[j].y,x5[j].x};
        }
        wsync();                   // a1 reads done before next a3 writes
        if (c0<1){
            #pragma unroll
            for (int cc=0;cc<8;++cc) kv[cc]=kv2[cc];
            #pragma unroll
            for (int j=0;j<5;++j) sv[j]=sv2[j];
        }
    }
    // combine halves: half1 deposits acc in its own LDS row buffer
    if (half == 1){
        #pragma unroll
        for (int j=0;j<5;++j) A[t + 64*j] = acc[j];
    }
    __syncthreads();
    if (half == 0){
        long obase = ((long)cg*NS + s)*HW + h*NDIM;
        #pragma unroll
        for (int j=0;j<5;++j){
            int idx = t + 64*j;
            part[obase+idx] = acc[j] + bufA[4+rl][idx];
        }
    }
}

// ---------------------------------------------------------------------------
__global__ __launch_bounds__(256) void k_rhs_fin(
    const v2f* __restrict__ part, const v2f* __restrict__ Iin,
    v2f* __restrict__ r, v2f* __restrict__ x, float* __restrict__ scal)
{
    __shared__ float red[256];
    int gid = blockIdx.x*blockDim.x + threadIdx.x;
    int gsz = gridDim.x*blockDim.x;
    float rs = 0.f;
    const int NV = NS*HW;
    for (int i = gid; i < NV; i += gsz){
        int w = i % NDIM; int h = (i/NDIM)%NDIM; int s = i/HW;
        v2f iv = Iin[((long)s*NDIM + sh160(h))*NDIM + sh160(w)];
        v2f rr = part[i] + part[NV+i] + part[2*NV+i] + part[3*NV+i] + iv*RHO_;
        r[i] = rr;
        x[i] = (v2f){0.f,0.f};
        rs += rr.x*rr.x + rr.y*rr.y;
    }
    red[threadIdx.x]=rs; __syncthreads();
    for (int o=128;o>0;o>>=1){ if (threadIdx.x<o) red[threadIdx.x]+=red[threadIdx.x+o]; __syncthreads(); }
    if (threadIdx.x==0) atomicAdd(&scal[0], red[0]);
}

// ---------------------------------------------------------------------------
__global__ __launch_bounds__(256) void k_update(
    v2f* __restrict__ x, v2f* __restrict__ r,
    const v2f* __restrict__ p, const v2f* __restrict__ part,
    float* __restrict__ scal, int iter)
{
    __shared__ float red[256];
    float alpha = scal[iter] / (scal[16+iter] + 1e-12f);
    int gid = blockIdx.x*blockDim.x + threadIdx.x;
    int gsz = gridDim.x*blockDim.x;
    float rs = 0.f;
    const int NV = NS*HW;
    for (int i = gid; i < NV; i += gsz){
        v2f pvv=p[i];
        v2f av = part[i] + part[NV+i] + part[2*NV+i] + part[3*NV+i] + pvv*RHO_;
        v2f xv = x[i] + pvv*alpha;
        v2f rv = r[i] - av*alpha;
        x[i]=xv; r[i]=rv;
        rs += rv.x*rv.x + rv.y*rv.y;
    }
    red[threadIdx.x]=rs; __syncthreads();
    for (int o=128;o>0;o>>=1){ if (threadIdx.x<o) red[threadIdx.x]+=red[threadIdx.x+o]; __syncthreads(); }
    if (threadIdx.x==0) atomicAdd(&scal[iter+1], red[0]);
}

__global__ void k_final(const v2f* __restrict__ x, v2f* __restrict__ out)
{
    int gid = blockIdx.x*blockDim.x + threadIdx.x;
    int gsz = gridDim.x*blockDim.x;
    for (int i = gid; i < NS*HW; i += gsz){
        int w = i % NDIM; int h = (i/NDIM)%NDIM; int s = i/HW;
        out[i] = x[(long)s*HW + sh160(h)*NDIM + sh160(w)];
    }
}

extern "C" void kernel_launch(void* const* d_in, const int* in_sizes, int n_in,
                              void* d_out, int out_size, void* d_ws, size_t ws_size,
                              hipStream_t stream) {
    (void)in_sizes; (void)n_in; (void)out_size; (void)ws_size;
    const v2f* kin  = (const v2f*)d_in[0];
    const v2f* Iin  = (const v2f*)d_in[1];
    const v2f* csm  = (const v2f*)d_in[2];
    const float* mask = (const float*)d_in[3];

    char* w = (char*)d_ws;
    size_t off = 0;
    float* scal = (float*)(w+off);  off += 1024;
    h2* sP    = (h2*)(w+off);  off += (size_t)NC*HW*4;
    float* mscT = (float*)(w+off); off += (size_t)NS*HW*4;
    h2* K     = (h2*)(w+off);  off += (size_t)NS*NC*HW*4;
    v2f* x    = (v2f*)(w+off); off += (size_t)NS*HW*8;
    v2f* r    = (v2f*)(w+off); off += (size_t)NS*HW*8;
    v2f* pA   = (v2f*)(w+off); off += (size_t)NS*HW*8;
    v2f* pB   = (v2f*)(w+off); off += (size_t)NS*HW*8;
    v2f* part = (v2f*)(w+off); off += (size_t)4*NS*HW*8;

    k_prep<<<2048,256,0,stream>>>(kin, mask, csm, sP, mscT, K, scal);
    k_passB<<<NS*NC*20,1024,0,stream>>>(K, mscT, scal, 0, 0);
    k_passC2<<<NS*80*4,512,0,stream>>>(K, sP, part);
    k_rhs_fin<<<640,256,0,stream>>>(part, Iin, r, x, scal);

    for (int it=0; it<CG_ITERS; ++it){
        v2f* pNew = (it&1)? pB : pA;
        v2f* pOld = (it&1)? pA : pB;
        k_passA<<<NS*80*4,512,0,stream>>>(r, pOld, pNew, sP, K, scal, it);
        k_passB<<<NS*NC*20,1024,0,stream>>>(K, mscT, scal, it, 1);
        k_passC2<<<NS*80*4,512,0,stream>>>(K, sP, part);
        k_update<<<640,256,0,stream>>>(x, r, pNew, part, scal, it);
    }
    k_final<<<512,256,0,stream>>>(x, (v2f*)d_out);
}

// Round 13
// 1422.141 us; speedup vs baseline: 1.0904x; 1.0146x over previous
//
#include <hip/hip_runtime.h>
#include <math.h>

// ---------------------------------------------------------------------------
// SENSE CG reconstruction, B=1, S=4, C=16, H=W=320, rho=0.1, 15 CG iters.
// R6: FFT-320 = Stockham {5,8,8}; R7: packed-fp32 complex math (v2f);
// R8: K/sP in fp16; R9: passB 16-col tiles, h8v (16B/lane) global access.
// R12: row kernels 512thr/8-wave; R14: Parseval pAp in passB (1459);
// R17: passB LDS pad L=325 (1443). R13/R15/R16 (REVERTED).
// R18: part buffer in fp16 (4 B/complex): passC2-write + rhs_fin/update-read
//     drop 13 MB/iter. Proven lever class (dtype shrink on bulk streams,
//     cf. R8/R9). part values ~ same magnitude class as K (already fp16);
//     expected absmax <= 0.0625.
// ---------------------------------------------------------------------------

#define NDIM 320
#define HHALF 160
#define HW (NDIM*NDIM)
#define NS 4
#define NC 16
#define RHO_ 0.1f
#define CG_ITERS 15

typedef float v2f __attribute__((ext_vector_type(2)));
typedef _Float16 h2 __attribute__((ext_vector_type(2)));
typedef _Float16 h8v __attribute__((ext_vector_type(8)));

__device__ __forceinline__ v2f h2f(h2 h){ return (v2f){(float)h.x, (float)h.y}; }
__device__ __forceinline__ h2 f2h(v2f v){ return (h2){(_Float16)v.x, (_Float16)v.y}; }

__device__ __forceinline__ void wsync(){
    __builtin_amdgcn_fence(__ATOMIC_ACQ_REL, "wavefront");
    __builtin_amdgcn_wave_barrier();
}

__device__ __forceinline__ float wred(float v){
    #pragma unroll
    for (int o=32;o>0;o>>=1) v += __shfl_down(v,o,64);
    return v;  // valid on lane 0
}

// complex mul: 2 packed FMAs
__device__ __forceinline__ v2f cmulf(v2f a, v2f b){
    return (v2f){a.x,a.x}*b + (v2f){-a.y,a.y}*(v2f){b.y,b.x};
}

template<int SIGMA>
__device__ __forceinline__ v2f cmulw(v2f a, v2f w){
    v2f wb = (SIGMA<0) ? w : (v2f){w.x, -w.y};
    return cmulf(a, wb);
}

template<int SIGMA>
__device__ __forceinline__ v2f mulj(v2f z){  // SIGMA*i*z
    return (v2f){ -(float)SIGMA*z.y, (float)SIGMA*z.x };
}

template<int SIGMA>
__device__ __forceinline__ void radix5(const v2f* u, v2f* v){
    const float C1 = 0.30901699437494742f, S1 = 0.95105651629515357f;
    const float C2 = -0.80901699437494745f, S2 = 0.58778525229247312f;
    v2f t1=u[1]+u[4], t2=u[2]+u[3], t3=u[1]-u[4], t4=u[2]-u[3];
    v[0] = u[0] + t1 + t2;
    v2f m1 = u[0] + t1*C1 + t2*C2;
    v2f m2 = u[0] + t1*C2 + t2*C1;
    v2f n1 = t3*S1 + t4*S2;
    v2f n2 = t3*S2 - t4*S1;
    v2f j1 = mulj<SIGMA>(n1), j2 = mulj<SIGMA>(n2);
    v[1]=m1+j1; v[4]=m1-j1; v[2]=m2+j2; v[3]=m2-j2;
}

template<int SIGMA>
__device__ __forceinline__ void dft8(const v2f* u, v2f* y){
    const float C = 0.70710678118654752f;
    v2f a0=u[0]+u[4], a1=u[0]-u[4];
    v2f a2=u[2]+u[6], a3=u[2]-u[6];
    v2f a4=u[1]+u[5], a5=u[1]-u[5];
    v2f a6=u[3]+u[7], a7=u[3]-u[7];
    v2f j3 = mulj<SIGMA>(a3);
    v2f E0=a0+a2, E2=a0-a2;
    v2f E1=a1+j3, E3=a1-j3;
    v2f j7 = mulj<SIGMA>(a7);
    v2f O0=a4+a6, O2=a4-a6;
    v2f O1=a5+j7, O3=a5-j7;
    v2f W1 = (O1 + mulj<SIGMA>(O1)) * C;
    v2f jO2 = mulj<SIGMA>(O2);
    v2f W3 = (mulj<SIGMA>(O3) - O3) * C;
    y[0]=E0+O0; y[4]=E0-O0;
    y[1]=E1+W1; y[5]=E1-W1;
    y[2]=E2+jO2; y[6]=E2-jO2;
    y[3]=E3+W3; y[7]=E3-W3;
}

// ---- forward Stockham {5,8,8}: natural in -> natural out -------------------
template<int SIGMA>
__device__ __forceinline__ void s1_from_regs(v2f* __restrict__ A, int t,
                                             const v2f* u5){
    v2f v[5];
    radix5<SIGMA>(u5, v);
    #pragma unroll
    for (int c=0;c<5;++c) A[5*t + c] = v[c];
}

template<int SIGMA>
__device__ __forceinline__ void s1_stage(v2f* __restrict__ A, int t){
    v2f u[5];
    #pragma unroll
    for (int q=0;q<5;++q) u[q] = A[t + 64*q];
    wsync();
    s1_from_regs<SIGMA>(A, t, u);
}

template<int SIGMA>
__device__ __forceinline__ void s2_stage(v2f* __restrict__ A, int t, v2f w40){
    if (t < 40){
        v2f u[8];
        #pragma unroll
        for (int q=0;q<8;++q) u[q] = A[t + 40*q];
        wsync();
        v2f wc = w40;
        u[1] = cmulw<SIGMA>(u[1], wc);
        #pragma unroll
        for (int q=2;q<8;++q){ wc = cmulf(wc, w40); u[q] = cmulw<SIGMA>(u[q], wc); }
        v2f v[8];
        dft8<SIGMA>(u, v);
        int k = t % 5, jb = t / 5;
        int base = jb*40 + k;
        #pragma unroll
        for (int c=0;c<8;++c) A[base + 5*c] = v[c];
    }
}

template<int SIGMA>
__device__ __forceinline__ void s3_toregs(const v2f* __restrict__ A, int t,
                                          v2f w320, v2f* v){
    if (t < 40){
        v2f u[8];
        #pragma unroll
        for (int q=0;q<8;++q) u[q] = A[t + 40*q];
        v2f wc = w320;
        u[1] = cmulw<SIGMA>(u[1], wc);
        #pragma unroll
        for (int q=2;q<8;++q){ wc = cmulf(wc, w320); u[q] = cmulw<SIGMA>(u[q], wc); }
        dft8<SIGMA>(u, v);
    }
}

// ---- adjoint network (unnormalized inverse) -------------------------------
template<int SIGMA>
__device__ __forceinline__ void a3_fromregs(v2f* __restrict__ A, int t,
                                            v2f w320, const v2f* vin){
    if (t < 40){
        v2f u[8];
        dft8<SIGMA>(vin, u);
        v2f wc = w320;
        u[1] = cmulw<SIGMA>(u[1], wc);
        #pragma unroll
        for (int q=2;q<8;++q){ wc = cmulf(wc, w320); u[q] = cmulw<SIGMA>(u[q], wc); }
        #pragma unroll
        for (int q=0;q<8;++q) A[t + 40*q] = u[q];
    }
}

template<int SIGMA>
__device__ __forceinline__ void a2_stage(v2f* __restrict__ A, int t, v2f w40){
    if (t < 40){
        int k = t % 5, jb = t / 5;
        int base = jb*40 + k;
        v2f v[8];
        #pragma unroll
        for (int c=0;c<8;++c) v[c] = A[base + 5*c];
        wsync();
        v2f u[8];
        dft8<SIGMA>(v, u);
        v2f wc = w40;
        u[1] = cmulw<SIGMA>(u[1], wc);
        #pragma unroll
        for (int q=2;q<8;++q){ wc = cmulf(wc, w40); u[q] = cmulw<SIGMA>(u[q], wc); }
        #pragma unroll
        for (int q=0;q<8;++q) A[t + 40*q] = u[q];
    }
}

template<int SIGMA>
__device__ __forceinline__ void a1_toregs(const v2f* __restrict__ A, int t,
                                          v2f* out5){
    v2f v[5];
    #pragma unroll
    for (int c=0;c<5;++c) v[c] = A[5*t + c];
    radix5<SIGMA>(v, out5);
}

__device__ __forceinline__ void make_w(int t, v2f& w40, v2f& w320){
    float sn, cs;
    const float n2pi = -6.283185307179586f;
    __sincosf(n2pi*(float)(t%5)/40.f, &sn, &cs); w40  = (v2f){cs, sn};
    __sincosf(n2pi*(float)t/320.f,    &sn, &cs); w320 = (v2f){cs, sn};
}

__device__ __forceinline__ int sh160(int i){ return i < HHALF ? i + HHALF : i - HHALF; }

// ---------------------------------------------------------------------------
__global__ void k_prep(const v2f* __restrict__ kin, const float* __restrict__ mask,
                       const v2f* __restrict__ csm, h2* __restrict__ sP,
                       float* __restrict__ mscT, h2* __restrict__ K,
                       float* __restrict__ scal)
{
    int gid = blockIdx.x*blockDim.x + threadIdx.x;
    int gsz = gridDim.x*blockDim.x;
    if (gid < 64) scal[gid] = 0.f;
    for (int i = gid; i < NC*HW; i += gsz){
        int w = i % NDIM; int h = (i/NDIM) % NDIM; int c = i/HW;
        sP[i] = f2h(csm[(c*NDIM + sh160(h))*NDIM + sh160(w)]);
    }
    for (int i = gid; i < NS*HW; i += gsz){
        int h = i % NDIM; int wc = (i/NDIM)%NDIM; int s = i/HW;
        float m = mask[(s*NDIM + sh160(h))*NDIM + sh160(wc)];
        mscT[i] = m*m*(1.0f/102400.0f);
    }
    for (int i = gid; i < NS*NC*HW; i += gsz){
        int w = i % NDIM; int h = (i/NDIM)%NDIM; int sc = i/HW;
        int s = sc >> 4;
        int hs = sh160(h), ws = sh160(w);
        float m = mask[(s*NDIM + hs)*NDIM + ws];
        v2f kv = kin[((long)sc*NDIM + hs)*NDIM + ws];
        float f = m*(1.0f/320.0f);
        K[i] = f2h(kv * f);
    }
}

// ---------------------------------------------------------------------------
// PassA (R12): p = r + beta*p fused; K[s,c,h,:] = rowFFT(s'_c .* p).
// grid = S*80*4 ; 512 thr = 8 waves: waves 0-3 rows x coils {c,c+1},
// waves 4-7 same rows x coils {c+2,c+3}. pv staged via LDS (half0 loads).
__global__ __launch_bounds__(512) void k_passA(
    const v2f* __restrict__ rv_, const v2f* __restrict__ pOld,
    v2f* __restrict__ pNew, const h2* __restrict__ sP,
    h2* __restrict__ K, float* __restrict__ scal, int iter)
{
    int bid = blockIdx.x;
    int cg = bid & 3;
    int hg = (bid>>2) % 80;
    int s  = bid / (4*80);
    int tid = threadIdx.x;
    int wv = tid>>6; int rl = wv&3; int half = wv>>2; int t = tid&63;
    int h = hg*4 + rl;
    __shared__ v2f bufA[8][NDIM];
    __shared__ v2f pbuf[4][NDIM];
    v2f* A = &bufA[wv][0];
    v2f w40, w320; make_w(t, w40, w320);
    long base = (long)s*HW + h*NDIM;
    v2f pv[5];
    if (half == 0){
        float beta = 0.f;
        if (iter > 0) beta = scal[iter] / (scal[iter-1] + 1e-12f);
        #pragma unroll
        for (int j=0;j<5;++j){
            int idx = t + 64*j;
            v2f rr = rv_[base+idx];
            if (iter > 0){
                v2f pp = pOld[base+idx];
                pv[j] = rr + pp*beta;
            } else pv[j] = rr;
            pbuf[rl][idx] = pv[j];
        }
        if (cg == 0){
            float d = 0.f;
            #pragma unroll
            for (int j=0;j<5;++j){
                pNew[base + t + 64*j] = pv[j];
                d += pv[j].x*pv[j].x + pv[j].y*pv[j].y;
            }
            float wd = wred(d);
            if (t==0) atomicAdd(&scal[16+iter], RHO_*wd);
        }
    }
    __syncthreads();
    if (half == 1){
        #pragma unroll
        for (int j=0;j<5;++j) pv[j] = pbuf[rl][t + 64*j];
    }
    int c = cg*4 + half*2;
    const h2* srow = sP + (long)c*HW + h*NDIM;
    v2f sv[5];
    #pragma unroll
    for (int j=0;j<5;++j) sv[j] = h2f(srow[t+64*j]);
    #pragma unroll
    for (int c0=0;c0<2;++c0){
        v2f u5[5];
        #pragma unroll
        for (int j=0;j<5;++j) u5[j] = cmulf(sv[j], pv[j]);
        v2f sv2[5];
        if (c0<1){
            const h2* sr2 = srow + (long)HW;
            #pragma unroll
            for (int j=0;j<5;++j) sv2[j] = h2f(sr2[t+64*j]);
        }
        wsync();                                   // prior-iter S3 reads done
        s1_from_regs<-1>(A, t, u5);
        wsync();
        s2_stage<-1>(A, t, w40);
        wsync();
        v2f v8[8];
        s3_toregs<-1>(A, t, w320, v8);
        long kb = ((long)(s*NC + c + c0))*HW + h*NDIM;
        if (t < 40){
            #pragma unroll
            for (int cc=0;cc<8;++cc) K[kb + t + 40*cc] = f2h(v8[cc]);
        }
        if (c0<1){
            #pragma unroll
            for (int j=0;j<5;++j) sv[j]=sv2[j];
        }
    }
}

// ---------------------------------------------------------------------------
// PassB (R9 structure + Parseval pAp, R17 pad L=325): 16-column LDS tile;
// h8v (16B/lane). colFFT -> [pap += mv*|v8|^2] -> mask -> colIFFT
// (doMask=1), or colFFT<+1> only (doMask=0). One pap atomic per block.
__global__ __launch_bounds__(1024) void k_passB(h2* __restrict__ K,
    const float* __restrict__ mscT, float* __restrict__ scal, int iter,
    int doMask)
{
    constexpr int L = 325;
    int bid = blockIdx.x;
    int wt = bid % 20;
    int sc = bid / 20;
    int s = sc >> 4;
    int tid = threadIdx.x;
    int col = tid >> 6;          // 0..15
    int t = tid & 63;
    int w0 = wt*16;
    __shared__ v2f bufA[16][L];
    __shared__ float redP[16];
    v2f w40, w320; make_w(t, w40, w320);
    float mv[8];
    if (doMask && t < 40){
        const float* mcol = mscT + (long)s*HW + (long)(w0+col)*NDIM;
        #pragma unroll
        for (int cc=0;cc<8;++cc) mv[cc] = mcol[t+40*cc];
    }
    long gb = (long)sc*HW + w0;
    for (int i = tid; i < NDIM*4; i += 1024){
        int row = i >> 2, ch = i & 3;
        h8v val = *(const h8v*)&K[gb + (long)row*NDIM + ch*4];
        #pragma unroll
        for (int k=0;k<4;++k)
            bufA[ch*4+k][row] = (v2f){(float)val[2*k], (float)val[2*k+1]};
    }
    __syncthreads();
    v2f* A = &bufA[col][0];
    if (doMask){
        s1_stage<-1>(A, t);
        wsync();
        s2_stage<-1>(A, t, w40);
        wsync();
        v2f v8[8];
        s3_toregs<-1>(A, t, w320, v8);
        float pap = 0.f;
        if (t < 40){
            #pragma unroll
            for (int cc=0;cc<8;++cc){
                float m = mv[cc];
                pap += m*(v8[cc].x*v8[cc].x + v8[cc].y*v8[cc].y);
                v8[cc] = v8[cc]*m;
            }
        }
        {
            float wp = wred(pap);
            if (t==0) redP[col] = wp;
        }
        wsync();
        a3_fromregs<1>(A, t, w320, v8);
        wsync();
        a2_stage<1>(A, t, w40);
        wsync();
        v2f x5[5];
        a1_toregs<1>(A, t, x5);
        wsync();
        #pragma unroll
        for (int q=0;q<5;++q) A[t + 64*q] = x5[q];
    } else {
        s1_stage<1>(A, t);
        wsync();
        s2_stage<1>(A, t, w40);
        wsync();
        v2f v8[8];
        s3_toregs<1>(A, t, w320, v8);
        wsync();
        if (t < 40){
            #pragma unroll
            for (int cc=0;cc<8;++cc) A[t + 40*cc] = v8[cc];
        }
    }
    __syncthreads();
    for (int i = tid; i < NDIM*4; i += 1024){
        int row = i >> 2, ch = i & 3;
        h8v val;
        #pragma unroll
        for (int k=0;k<4;++k){
            v2f u = bufA[ch*4+k][row];
            val[2*k] = (_Float16)u.x; val[2*k+1] = (_Float16)u.y;
        }
        *(h8v*)&K[gb + (long)row*NDIM + ch*4] = val;
    }
    if (doMask && tid==0){
        float sum = 0.f;
        #pragma unroll
        for (int k=0;k<16;++k) sum += redP[k];
        atomicAdd(&scal[16+iter], sum);
    }
}

// ---------------------------------------------------------------------------
// PassC2 (R12 FFT structure, dot work removed; R18 fp16 part): row inverse
// of 4 coils (2 per wave-half), halves combined via LDS; conj(s')-combine
// into part[cg] (fp16). grid = S*80*4 ; 512 thr = 8 waves.
__global__ __launch_bounds__(512) void k_passC2(
    const h2* __restrict__ K, const h2* __restrict__ sP,
    h2* __restrict__ part)
{
    int bid = blockIdx.x;
    int cg = bid & 3;
    int hg = (bid>>2) % 80;
    int s  = bid / (4*80);
    int tid = threadIdx.x;
    int wv = tid>>6; int rl = wv&3; int half = wv>>2; int t = tid&63;
    int h = hg*4 + rl;
    __shared__ v2f bufA[8][NDIM];
    v2f* A = &bufA[wv][0];
    v2f w40, w320; make_w(t, w40, w320);
    int c = cg*4 + half*2;
    long kb0 = ((long)(s*NC + c))*HW + h*NDIM;
    const h2* srow = sP + (long)c*HW + h*NDIM;
    v2f kv[8], sv[5];
    if (t < 40){
        #pragma unroll
        for (int cc=0;cc<8;++cc) kv[cc] = h2f(K[kb0 + t + 40*cc]);
    }
    #pragma unroll
    for (int j=0;j<5;++j) sv[j] = h2f(srow[t+64*j]);
    v2f acc[5];
    #pragma unroll
    for (int j=0;j<5;++j) acc[j]=(v2f){0.f,0.f};
    #pragma unroll
    for (int c0=0;c0<2;++c0){
        a3_fromregs<1>(A, t, w320, kv);
        v2f kv2[8], sv2[5];
        if (c0<1){
            long kb = kb0 + (long)HW;
            const h2* sr2 = srow + (long)HW;
            if (t < 40){
                #pragma unroll
                for (int cc=0;cc<8;++cc) kv2[cc] = h2f(K[kb + t + 40*cc]);
            }
            #pragma unroll
            for (int j=0;j<5;++j) sv2[j] = h2f(sr2[t+64*j]);
        }
        wsync();
        a2_stage<1>(A, t, w40);
        wsync();
        v2f x5[5];
        a1_toregs<1>(A, t, x5);
        #pragma unroll
        for (int j=0;j<5;++j){
            // acc += conj(s)*u  (2 packed FMAs)
            acc[j] += (v2f){sv[j].x,sv[j].x}*x5[j]
                    + (v2f){sv[j].y,-sv[j].y}*(v2f){x5[j].y,x5[j].x};
        }
        wsync();                   // a1 reads done before next a3 writes
        if (c0<1){
            #pragma unroll
            for (int cc=0;cc<8;++cc) kv[cc]=kv2[cc];
            #pragma unroll
            for (int j=0;j<5;++j) sv[j]=sv2[j];
        }
    }
    // combine halves: half1 deposits acc in its own LDS row buffer
    if (half == 1){
        #pragma unroll
        for (int j=0;j<5;++j) A[t + 64*j] = acc[j];
    }
    __syncthreads();
    if (half == 0){
        long obase = ((long)cg*NS + s)*HW + h*NDIM;
        #pragma unroll
        for (int j=0;j<5;++j){
            int idx = t + 64*j;
            part[obase+idx] = f2h(acc[j] + bufA[4+rl][idx]);
        }
    }
}

// ---------------------------------------------------------------------------
__global__ __launch_bounds__(256) void k_rhs_fin(
    const h2* __restrict__ part, const v2f* __restrict__ Iin,
    v2f* __restrict__ r, v2f* __restrict__ x, float* __restrict__ scal)
{
    __shared__ float red[256];
    int gid = blockIdx.x*blockDim.x + threadIdx.x;
    int gsz = gridDim.x*blockDim.x;
    float rs = 0.f;
    const int NV = NS*HW;
    for (int i = gid; i < NV; i += gsz){
        int w = i % NDIM; int h = (i/NDIM)%NDIM; int s = i/HW;
        v2f iv = Iin[((long)s*NDIM + sh160(h))*NDIM + sh160(w)];
        v2f rr = h2f(part[i]) + h2f(part[NV+i]) + h2f(part[2*NV+i])
               + h2f(part[3*NV+i]) + iv*RHO_;
        r[i] = rr;
        x[i] = (v2f){0.f,0.f};
        rs += rr.x*rr.x + rr.y*rr.y;
    }
    red[threadIdx.x]=rs; __syncthreads();
    for (int o=128;o>0;o>>=1){ if (threadIdx.x<o) red[threadIdx.x]+=red[threadIdx.x+o]; __syncthreads(); }
    if (threadIdx.x==0) atomicAdd(&scal[0], red[0]);
}

// ---------------------------------------------------------------------------
__global__ __launch_bounds__(256) void k_update(
    v2f* __restrict__ x, v2f* __restrict__ r,
    const v2f* __restrict__ p, const h2* __restrict__ part,
    float* __restrict__ scal, int iter)
{
    __shared__ float red[256];
    float alpha = scal[iter] / (scal[16+iter] + 1e-12f);
    int gid = blockIdx.x*blockDim.x + threadIdx.x;
    int gsz = gridDim.x*blockDim.x;
    float rs = 0.f;
    const int NV = NS*HW;
    for (int i = gid; i < NV; i += gsz){
        v2f pvv=p[i];
        v2f av = h2f(part[i]) + h2f(part[NV+i]) + h2f(part[2*NV+i])
               + h2f(part[3*NV+i]) + pvv*RHO_;
        v2f xv = x[i] + pvv*alpha;
        v2f rv = r[i] - av*alpha;
        x[i]=xv; r[i]=rv;
        rs += rv.x*rv.x + rv.y*rv.y;
    }
    red[threadIdx.x]=rs; __syncthreads();
    for (int o=128;o>0;o>>=1){ if (threadIdx.x<o) red[threadIdx.x]+=red[threadIdx.x+o]; __syncthreads(); }
    if (threadIdx.x==0) atomicAdd(&scal[iter+1], red[0]);
}

__global__ void k_final(const v2f* __restrict__ x, v2f* __restrict__ out)
{
    int gid = blockIdx.x*blockDim.x + threadIdx.x;
    int gsz = gridDim.x*blockDim.x;
    for (int i = gid; i < NS*HW; i += gsz){
        int w = i % NDIM; int h = (i/NDIM)%NDIM; int s = i/HW;
        out[i] = x[(long)s*HW + sh160(h)*NDIM + sh160(w)];
    }
}

extern "C" void kernel_launch(void* const* d_in, const int* in_sizes, int n_in,
                              void* d_out, int out_size, void* d_ws, size_t ws_size,
                              hipStream_t stream) {
    (void)in_sizes; (void)n_in; (void)out_size; (void)ws_size;
    const v2f* kin  = (const v2f*)d_in[0];
    const v2f* Iin  = (const v2f*)d_in[1];
    const v2f* csm  = (const v2f*)d_in[2];
    const float* mask = (const float*)d_in[3];

    char* w = (char*)d_ws;
    size_t off = 0;
    float* scal = (float*)(w+off);  off += 1024;
    h2* sP    = (h2*)(w+off);  off += (size_t)NC*HW*4;
    float* mscT = (float*)(w+off); off += (size_t)NS*HW*4;
    h2* K     = (h2*)(w+off);  off += (size_t)NS*NC*HW*4;
    v2f* x    = (v2f*)(w+off); off += (size_t)NS*HW*8;
    v2f* r    = (v2f*)(w+off); off += (size_t)NS*HW*8;
    v2f* pA   = (v2f*)(w+off); off += (size_t)NS*HW*8;
    v2f* pB   = (v2f*)(w+off); off += (size_t)NS*HW*8;
    h2* part  = (h2*)(w+off);  off += (size_t)4*NS*HW*4;

    k_prep<<<2048,256,0,stream>>>(kin, mask, csm, sP, mscT, K, scal);
    k_passB<<<NS*NC*20,1024,0,stream>>>(K, mscT, scal, 0, 0);
    k_passC2<<<NS*80*4,512,0,stream>>>(K, sP, part);
    k_rhs_fin<<<640,256,0,stream>>>(part, Iin, r, x, scal);

    for (int it=0; it<CG_ITERS; ++it){
        v2f* pNew = (it&1)? pB : pA;
        v2f* pOld = (it&1)? pA : pB;
        k_passA<<<NS*80*4,512,0,stream>>>(r, pOld, pNew, sP, K, scal, it);
        k_passB<<<NS*NC*20,1024,0,stream>>>(K, mscT, scal, it, 1);
        k_passC2<<<NS*80*4,512,0,stream>>>(K, sP, part);
        k_update<<<640,256,0,stream>>>(x, r, pNew, part, scal, it);
    }
    k_final<<<512,256,0,stream>>>(x, (v2f*)d_out);
}

// Round 14
// 1410.688 us; speedup vs baseline: 1.0993x; 1.0081x over previous
//
#include <hip/hip_runtime.h>
#include <math.h>

// ---------------------------------------------------------------------------
// SENSE CG reconstruction, B=1, S=4, C=16, H=W=320, rho=0.1, 15 CG iters.
// R6: FFT-320 = Stockham {5,8,8}; R7: packed-fp32 complex math (v2f);
// R8: K/sP in fp16; R9: passB 16-col tiles, h8v (16B/lane) global access.
// R12: row kernels 512thr/8-wave; R14: Parseval pAp in passB (1459);
// R17: passB LDS pad L=325 (1443); R18: fp16 part buffer (1422).
// R13/R15/R16 (REVERTED).
// R19: passB 2 columns/wave (512 thr, 8 waves, same 16-col tile): passB is
//     latency-bound (VALU 37%, HBM 16%, conflicts fixed) - each stage now
//     issues BOTH columns' LDS reads before waiting, doubling per-wave ILP
//     and sharing twiddle compute. R10's bundled regression attributed to
//     ix-map VALU tax + (512,4) reg cap - both absent here. passB only.
// ---------------------------------------------------------------------------

#define NDIM 320
#define HHALF 160
#define HW (NDIM*NDIM)
#define NS 4
#define NC 16
#define RHO_ 0.1f
#define CG_ITERS 15

typedef float v2f __attribute__((ext_vector_type(2)));
typedef _Float16 h2 __attribute__((ext_vector_type(2)));
typedef _Float16 h8v __attribute__((ext_vector_type(8)));

__device__ __forceinline__ v2f h2f(h2 h){ return (v2f){(float)h.x, (float)h.y}; }
__device__ __forceinline__ h2 f2h(v2f v){ return (h2){(_Float16)v.x, (_Float16)v.y}; }

__device__ __forceinline__ void wsync(){
    __builtin_amdgcn_fence(__ATOMIC_ACQ_REL, "wavefront");
    __builtin_amdgcn_wave_barrier();
}

__device__ __forceinline__ float wred(float v){
    #pragma unroll
    for (int o=32;o>0;o>>=1) v += __shfl_down(v,o,64);
    return v;  // valid on lane 0
}

// complex mul: 2 packed FMAs
__device__ __forceinline__ v2f cmulf(v2f a, v2f b){
    return (v2f){a.x,a.x}*b + (v2f){-a.y,a.y}*(v2f){b.y,b.x};
}

template<int SIGMA>
__device__ __forceinline__ v2f cmulw(v2f a, v2f w){
    v2f wb = (SIGMA<0) ? w : (v2f){w.x, -w.y};
    return cmulf(a, wb);
}

template<int SIGMA>
__device__ __forceinline__ v2f mulj(v2f z){  // SIGMA*i*z
    return (v2f){ -(float)SIGMA*z.y, (float)SIGMA*z.x };
}

template<int SIGMA>
__device__ __forceinline__ void radix5(const v2f* u, v2f* v){
    const float C1 = 0.30901699437494742f, S1 = 0.95105651629515357f;
    const float C2 = -0.80901699437494745f, S2 = 0.58778525229247312f;
    v2f t1=u[1]+u[4], t2=u[2]+u[3], t3=u[1]-u[4], t4=u[2]-u[3];
    v[0] = u[0] + t1 + t2;
    v2f m1 = u[0] + t1*C1 + t2*C2;
    v2f m2 = u[0] + t1*C2 + t2*C1;
    v2f n1 = t3*S1 + t4*S2;
    v2f n2 = t3*S2 - t4*S1;
    v2f j1 = mulj<SIGMA>(n1), j2 = mulj<SIGMA>(n2);
    v[1]=m1+j1; v[4]=m1-j1; v[2]=m2+j2; v[3]=m2-j2;
}

template<int SIGMA>
__device__ __forceinline__ void dft8(const v2f* u, v2f* y){
    const float C = 0.70710678118654752f;
    v2f a0=u[0]+u[4], a1=u[0]-u[4];
    v2f a2=u[2]+u[6], a3=u[2]-u[6];
    v2f a4=u[1]+u[5], a5=u[1]-u[5];
    v2f a6=u[3]+u[7], a7=u[3]-u[7];
    v2f j3 = mulj<SIGMA>(a3);
    v2f E0=a0+a2, E2=a0-a2;
    v2f E1=a1+j3, E3=a1-j3;
    v2f j7 = mulj<SIGMA>(a7);
    v2f O0=a4+a6, O2=a4-a6;
    v2f O1=a5+j7, O3=a5-j7;
    v2f W1 = (O1 + mulj<SIGMA>(O1)) * C;
    v2f jO2 = mulj<SIGMA>(O2);
    v2f W3 = (mulj<SIGMA>(O3) - O3) * C;
    y[0]=E0+O0; y[4]=E0-O0;
    y[1]=E1+W1; y[5]=E1-W1;
    y[2]=E2+jO2; y[6]=E2-jO2;
    y[3]=E3+W3; y[7]=E3-W3;
}

// ---- forward Stockham {5,8,8}: natural in -> natural out -------------------
template<int SIGMA>
__device__ __forceinline__ void s1_from_regs(v2f* __restrict__ A, int t,
                                             const v2f* u5){
    v2f v[5];
    radix5<SIGMA>(u5, v);
    #pragma unroll
    for (int c=0;c<5;++c) A[5*t + c] = v[c];
}

template<int SIGMA>
__device__ __forceinline__ void s1_stage(v2f* __restrict__ A, int t){
    v2f u[5];
    #pragma unroll
    for (int q=0;q<5;++q) u[q] = A[t + 64*q];
    wsync();
    s1_from_regs<SIGMA>(A, t, u);
}

template<int SIGMA>
__device__ __forceinline__ void s2_stage(v2f* __restrict__ A, int t, v2f w40){
    if (t < 40){
        v2f u[8];
        #pragma unroll
        for (int q=0;q<8;++q) u[q] = A[t + 40*q];
        wsync();
        v2f wc = w40;
        u[1] = cmulw<SIGMA>(u[1], wc);
        #pragma unroll
        for (int q=2;q<8;++q){ wc = cmulf(wc, w40); u[q] = cmulw<SIGMA>(u[q], wc); }
        v2f v[8];
        dft8<SIGMA>(u, v);
        int k = t % 5, jb = t / 5;
        int base = jb*40 + k;
        #pragma unroll
        for (int c=0;c<8;++c) A[base + 5*c] = v[c];
    }
}

template<int SIGMA>
__device__ __forceinline__ void s3_toregs(const v2f* __restrict__ A, int t,
                                          v2f w320, v2f* v){
    if (t < 40){
        v2f u[8];
        #pragma unroll
        for (int q=0;q<8;++q) u[q] = A[t + 40*q];
        v2f wc = w320;
        u[1] = cmulw<SIGMA>(u[1], wc);
        #pragma unroll
        for (int q=2;q<8;++q){ wc = cmulf(wc, w320); u[q] = cmulw<SIGMA>(u[q], wc); }
        dft8<SIGMA>(u, v);
    }
}

// ---- adjoint network (unnormalized inverse) -------------------------------
template<int SIGMA>
__device__ __forceinline__ void a3_fromregs(v2f* __restrict__ A, int t,
                                            v2f w320, const v2f* vin){
    if (t < 40){
        v2f u[8];
        dft8<SIGMA>(vin, u);
        v2f wc = w320;
        u[1] = cmulw<SIGMA>(u[1], wc);
        #pragma unroll
        for (int q=2;q<8;++q){ wc = cmulf(wc, w320); u[q] = cmulw<SIGMA>(u[q], wc); }
        #pragma unroll
        for (int q=0;q<8;++q) A[t + 40*q] = u[q];
    }
}

template<int SIGMA>
__device__ __forceinline__ void a2_stage(v2f* __restrict__ A, int t, v2f w40){
    if (t < 40){
        int k = t % 5, jb = t / 5;
        int base = jb*40 + k;
        v2f v[8];
        #pragma unroll
        for (int c=0;c<8;++c) v[c] = A[base + 5*c];
        wsync();
        v2f u[8];
        dft8<SIGMA>(v, u);
        v2f wc = w40;
        u[1] = cmulw<SIGMA>(u[1], wc);
        #pragma unroll
        for (int q=2;q<8;++q){ wc = cmulf(wc, w40); u[q] = cmulw<SIGMA>(u[q], wc); }
        #pragma unroll
        for (int q=0;q<8;++q) A[t + 40*q] = u[q];
    }
}

template<int SIGMA>
__device__ __forceinline__ void a1_toregs(const v2f* __restrict__ A, int t,
                                          v2f* out5){
    v2f v[5];
    #pragma unroll
    for (int c=0;c<5;++c) v[c] = A[5*t + c];
    radix5<SIGMA>(v, out5);
}

// ---- dual-column variants for passB (2 cols/wave ILP) ---------------------
template<int SIGMA>
__device__ __forceinline__ void s1_dual(v2f* __restrict__ A0,
                                        v2f* __restrict__ A1, int t){
    v2f a[5], b[5];
    #pragma unroll
    for (int q=0;q<5;++q){ a[q] = A0[t + 64*q]; b[q] = A1[t + 64*q]; }
    wsync();
    v2f va[5], vb[5];
    radix5<SIGMA>(a, va); radix5<SIGMA>(b, vb);
    #pragma unroll
    for (int c=0;c<5;++c){ A0[5*t + c] = va[c]; A1[5*t + c] = vb[c]; }
}

template<int SIGMA>
__device__ __forceinline__ void s2_dual(v2f* __restrict__ A0,
                                        v2f* __restrict__ A1, int t, v2f w40){
    if (t < 40){
        v2f a[8], b[8];
        #pragma unroll
        for (int q=0;q<8;++q){ a[q] = A0[t + 40*q]; b[q] = A1[t + 40*q]; }
        wsync();
        v2f wc = w40;
        a[1] = cmulw<SIGMA>(a[1], wc); b[1] = cmulw<SIGMA>(b[1], wc);
        #pragma unroll
        for (int q=2;q<8;++q){
            wc = cmulf(wc, w40);
            a[q] = cmulw<SIGMA>(a[q], wc); b[q] = cmulw<SIGMA>(b[q], wc);
        }
        v2f va[8], vb[8];
        dft8<SIGMA>(a, va); dft8<SIGMA>(b, vb);
        int k = t % 5, jb = t / 5;
        int base = jb*40 + k;
        #pragma unroll
        for (int c=0;c<8;++c){ A0[base + 5*c] = va[c]; A1[base + 5*c] = vb[c]; }
    }
}

template<int SIGMA>
__device__ __forceinline__ void s3_dual(const v2f* __restrict__ A0,
                                        const v2f* __restrict__ A1, int t,
                                        v2f w320, v2f* va, v2f* vb){
    if (t < 40){
        v2f a[8], b[8];
        #pragma unroll
        for (int q=0;q<8;++q){ a[q] = A0[t + 40*q]; b[q] = A1[t + 40*q]; }
        v2f wc = w320;
        a[1] = cmulw<SIGMA>(a[1], wc); b[1] = cmulw<SIGMA>(b[1], wc);
        #pragma unroll
        for (int q=2;q<8;++q){
            wc = cmulf(wc, w320);
            a[q] = cmulw<SIGMA>(a[q], wc); b[q] = cmulw<SIGMA>(b[q], wc);
        }
        dft8<SIGMA>(a, va); dft8<SIGMA>(b, vb);
    }
}

template<int SIGMA>
__device__ __forceinline__ void a3_dual(v2f* __restrict__ A0,
                                        v2f* __restrict__ A1, int t,
                                        v2f w320, const v2f* va, const v2f* vb){
    if (t < 40){
        v2f a[8], b[8];
        dft8<SIGMA>(va, a); dft8<SIGMA>(vb, b);
        v2f wc = w320;
        a[1] = cmulw<SIGMA>(a[1], wc); b[1] = cmulw<SIGMA>(b[1], wc);
        #pragma unroll
        for (int q=2;q<8;++q){
            wc = cmulf(wc, w320);
            a[q] = cmulw<SIGMA>(a[q], wc); b[q] = cmulw<SIGMA>(b[q], wc);
        }
        #pragma unroll
        for (int q=0;q<8;++q){ A0[t + 40*q] = a[q]; A1[t + 40*q] = b[q]; }
    }
}

template<int SIGMA>
__device__ __forceinline__ void a2_dual(v2f* __restrict__ A0,
                                        v2f* __restrict__ A1, int t, v2f w40){
    if (t < 40){
        int k = t % 5, jb = t / 5;
        int base = jb*40 + k;
        v2f a[8], b[8];
        #pragma unroll
        for (int c=0;c<8;++c){ a[c] = A0[base + 5*c]; b[c] = A1[base + 5*c]; }
        wsync();
        v2f ua[8], ub[8];
        dft8<SIGMA>(a, ua); dft8<SIGMA>(b, ub);
        v2f wc = w40;
        ua[1] = cmulw<SIGMA>(ua[1], wc); ub[1] = cmulw<SIGMA>(ub[1], wc);
        #pragma unroll
        for (int q=2;q<8;++q){
            wc = cmulf(wc, w40);
            ua[q] = cmulw<SIGMA>(ua[q], wc); ub[q] = cmulw<SIGMA>(ub[q], wc);
        }
        #pragma unroll
        for (int q=0;q<8;++q){ A0[t + 40*q] = ua[q]; A1[t + 40*q] = ub[q]; }
    }
}

template<int SIGMA>
__device__ __forceinline__ void a1_dual(const v2f* __restrict__ A0,
                                        const v2f* __restrict__ A1, int t,
                                        v2f* oa, v2f* ob){
    v2f a[5], b[5];
    #pragma unroll
    for (int c=0;c<5;++c){ a[c] = A0[5*t + c]; b[c] = A1[5*t + c]; }
    radix5<SIGMA>(a, oa); radix5<SIGMA>(b, ob);
}

__device__ __forceinline__ void make_w(int t, v2f& w40, v2f& w320){
    float sn, cs;
    const float n2pi = -6.283185307179586f;
    __sincosf(n2pi*(float)(t%5)/40.f, &sn, &cs); w40  = (v2f){cs, sn};
    __sincosf(n2pi*(float)t/320.f,    &sn, &cs); w320 = (v2f){cs, sn};
}

__device__ __forceinline__ int sh160(int i){ return i < HHALF ? i + HHALF : i - HHALF; }

// ---------------------------------------------------------------------------
__global__ void k_prep(const v2f* __restrict__ kin, const float* __restrict__ mask,
                       const v2f* __restrict__ csm, h2* __restrict__ sP,
                       float* __restrict__ mscT, h2* __restrict__ K,
                       float* __restrict__ scal)
{
    int gid = blockIdx.x*blockDim.x + threadIdx.x;
    int gsz = gridDim.x*blockDim.x;
    if (gid < 64) scal[gid] = 0.f;
    for (int i = gid; i < NC*HW; i += gsz){
        int w = i % NDIM; int h = (i/NDIM) % NDIM; int c = i/HW;
        sP[i] = f2h(csm[(c*NDIM + sh160(h))*NDIM + sh160(w)]);
    }
    for (int i = gid; i < NS*HW; i += gsz){
        int h = i % NDIM; int wc = (i/NDIM)%NDIM; int s = i/HW;
        float m = mask[(s*NDIM + sh160(h))*NDIM + sh160(wc)];
        mscT[i] = m*m*(1.0f/102400.0f);
    }
    for (int i = gid; i < NS*NC*HW; i += gsz){
        int w = i % NDIM; int h = (i/NDIM)%NDIM; int sc = i/HW;
        int s = sc >> 4;
        int hs = sh160(h), ws = sh160(w);
        float m = mask[(s*NDIM + hs)*NDIM + ws];
        v2f kv = kin[((long)sc*NDIM + hs)*NDIM + ws];
        float f = m*(1.0f/320.0f);
        K[i] = f2h(kv * f);
    }
}

// ---------------------------------------------------------------------------
// PassA (R12): p = r + beta*p fused; K[s,c,h,:] = rowFFT(s'_c .* p).
// grid = S*80*4 ; 512 thr = 8 waves: waves 0-3 rows x coils {c,c+1},
// waves 4-7 same rows x coils {c+2,c+3}. pv staged via LDS (half0 loads).
__global__ __launch_bounds__(512) void k_passA(
    const v2f* __restrict__ rv_, const v2f* __restrict__ pOld,
    v2f* __restrict__ pNew, const h2* __restrict__ sP,
    h2* __restrict__ K, float* __restrict__ scal, int iter)
{
    int bid = blockIdx.x;
    int cg = bid & 3;
    int hg = (bid>>2) % 80;
    int s  = bid / (4*80);
    int tid = threadIdx.x;
    int wv = tid>>6; int rl = wv&3; int half = wv>>2; int t = tid&63;
    int h = hg*4 + rl;
    __shared__ v2f bufA[8][NDIM];
    __shared__ v2f pbuf[4][NDIM];
    v2f* A = &bufA[wv][0];
    v2f w40, w320; make_w(t, w40, w320);
    long base = (long)s*HW + h*NDIM;
    v2f pv[5];
    if (half == 0){
        float beta = 0.f;
        if (iter > 0) beta = scal[iter] / (scal[iter-1] + 1e-12f);
        #pragma unroll
        for (int j=0;j<5;++j){
            int idx = t + 64*j;
            v2f rr = rv_[base+idx];
            if (iter > 0){
                v2f pp = pOld[base+idx];
                pv[j] = rr + pp*beta;
            } else pv[j] = rr;
            pbuf[rl][idx] = pv[j];
        }
        if (cg == 0){
            float d = 0.f;
            #pragma unroll
            for (int j=0;j<5;++j){
                pNew[base + t + 64*j] = pv[j];
                d += pv[j].x*pv[j].x + pv[j].y*pv[j].y;
            }
            float wd = wred(d);
            if (t==0) atomicAdd(&scal[16+iter], RHO_*wd);
        }
    }
    __syncthreads();
    if (half == 1){
        #pragma unroll
        for (int j=0;j<5;++j) pv[j] = pbuf[rl][t + 64*j];
    }
    int c = cg*4 + half*2;
    const h2* srow = sP + (long)c*HW + h*NDIM;
    v2f sv[5];
    #pragma unroll
    for (int j=0;j<5;++j) sv[j] = h2f(srow[t+64*j]);
    #pragma unroll
    for (int c0=0;c0<2;++c0){
        v2f u5[5];
        #pragma unroll
        for (int j=0;j<5;++j) u5[j] = cmulf(sv[j], pv[j]);
        v2f sv2[5];
        if (c0<1){
            const h2* sr2 = srow + (long)HW;
            #pragma unroll
            for (int j=0;j<5;++j) sv2[j] = h2f(sr2[t+64*j]);
        }
        wsync();                                   // prior-iter S3 reads done
        s1_from_regs<-1>(A, t, u5);
        wsync();
        s2_stage<-1>(A, t, w40);
        wsync();
        v2f v8[8];
        s3_toregs<-1>(A, t, w320, v8);
        long kb = ((long)(s*NC + c + c0))*HW + h*NDIM;
        if (t < 40){
            #pragma unroll
            for (int cc=0;cc<8;++cc) K[kb + t + 40*cc] = f2h(v8[cc]);
        }
        if (c0<1){
            #pragma unroll
            for (int j=0;j<5;++j) sv[j]=sv2[j];
        }
    }
}

// ---------------------------------------------------------------------------
// PassB (R9 tiles + Parseval pAp + R17 pad + R19 dual-column): 16-column LDS
// tile; h8v (16B/lane); 512 thr = 8 waves, wave wv handles cols 2wv,2wv+1.
// Each stage issues both columns' LDS reads before waiting (2x ILP, shared
// twiddles). colFFT -> [pap] -> mask -> colIFFT (doMask=1) or colFFT<+1>
// only (doMask=0). One pap atomic per block.
__global__ __launch_bounds__(512) void k_passB(h2* __restrict__ K,
    const float* __restrict__ mscT, float* __restrict__ scal, int iter,
    int doMask)
{
    constexpr int L = 325;
    int bid = blockIdx.x;
    int wt = bid % 20;
    int sc = bid / 20;
    int s = sc >> 4;
    int tid = threadIdx.x;
    int wv = tid >> 6;           // 0..7
    int t = tid & 63;
    int w0 = wt*16;
    __shared__ v2f bufA[16][L];
    __shared__ float redP[8];
    v2f w40, w320; make_w(t, w40, w320);
    float mvA[8], mvB[8];
    if (doMask && t < 40){
        const float* mA = mscT + (long)s*HW + (long)(w0+2*wv)*NDIM;
        const float* mB = mA + NDIM;
        #pragma unroll
        for (int cc=0;cc<8;++cc){ mvA[cc] = mA[t+40*cc]; mvB[cc] = mB[t+40*cc]; }
    }
    long gb = (long)sc*HW + w0;
    for (int i = tid; i < NDIM*4; i += 512){
        int row = i >> 2, ch = i & 3;
        h8v val = *(const h8v*)&K[gb + (long)row*NDIM + ch*4];
        #pragma unroll
        for (int k=0;k<4;++k)
            bufA[ch*4+k][row] = (v2f){(float)val[2*k], (float)val[2*k+1]};
    }
    __syncthreads();
    v2f* A0 = &bufA[2*wv][0];
    v2f* A1 = &bufA[2*wv+1][0];
    if (doMask){
        s1_dual<-1>(A0, A1, t);
        wsync();
        s2_dual<-1>(A0, A1, t, w40);
        wsync();
        v2f v8A[8], v8B[8];
        s3_dual<-1>(A0, A1, t, w320, v8A, v8B);
        float pap = 0.f;
        if (t < 40){
            #pragma unroll
            for (int cc=0;cc<8;++cc){
                float mA = mvA[cc], mB = mvB[cc];
                pap += mA*(v8A[cc].x*v8A[cc].x + v8A[cc].y*v8A[cc].y)
                     + mB*(v8B[cc].x*v8B[cc].x + v8B[cc].y*v8B[cc].y);
                v8A[cc] = v8A[cc]*mA;
                v8B[cc] = v8B[cc]*mB;
            }
        }
        {
            float wp = wred(pap);
            if (t==0) redP[wv] = wp;
        }
        wsync();
        a3_dual<1>(A0, A1, t, w320, v8A, v8B);
        wsync();
        a2_dual<1>(A0, A1, t, w40);
        wsync();
        v2f x5A[5], x5B[5];
        a1_dual<1>(A0, A1, t, x5A, x5B);
        wsync();
        #pragma unroll
        for (int q=0;q<5;++q){ A0[t + 64*q] = x5A[q]; A1[t + 64*q] = x5B[q]; }
    } else {
        s1_dual<1>(A0, A1, t);
        wsync();
        s2_dual<1>(A0, A1, t, w40);
        wsync();
        v2f v8A[8], v8B[8];
        s3_dual<1>(A0, A1, t, w320, v8A, v8B);
        wsync();
        if (t < 40){
            #pragma unroll
            for (int cc=0;cc<8;++cc){ A0[t + 40*cc] = v8A[cc]; A1[t + 40*cc] = v8B[cc]; }
        }
    }
    __syncthreads();
    for (int i = tid; i < NDIM*4; i += 512){
        int row = i >> 2, ch = i & 3;
        h8v val;
        #pragma unroll
        for (int k=0;k<4;++k){
            v2f u = bufA[ch*4+k][row];
            val[2*k] = (_Float16)u.x; val[2*k+1] = (_Float16)u.y;
        }
        *(h8v*)&K[gb + (long)row*NDIM + ch*4] = val;
    }
    if (doMask && tid==0){
        float sum = 0.f;
        #pragma unroll
        for (int k=0;k<8;++k) sum += redP[k];
        atomicAdd(&scal[16+iter], sum);
    }
}

// ---------------------------------------------------------------------------
// PassC2 (R12 FFT structure; R18 fp16 part): row inverse of 4 coils
// (2 per wave-half), halves combined via LDS; conj(s')-combine into
// part[cg] (fp16). grid = S*80*4 ; 512 thr = 8 waves.
__global__ __launch_bounds__(512) void k_passC2(
    const h2* __restrict__ K, const h2* __restrict__ sP,
    h2* __restrict__ part)
{
    int bid = blockIdx.x;
    int cg = bid & 3;
    int hg = (bid>>2) % 80;
    int s  = bid / (4*80);
    int tid = threadIdx.x;
    int wv = tid>>6; int rl = wv&3; int half = wv>>2; int t = tid&63;
    int h = hg*4 + rl;
    __shared__ v2f bufA[8][NDIM];
    v2f* A = &bufA[wv][0];
    v2f w40, w320; make_w(t, w40, w320);
    int c = cg*4 + half*2;
    long kb0 = ((long)(s*NC + c))*HW + h*NDIM;
    const h2* srow = sP + (long)c*HW + h*NDIM;
    v2f kv[8], sv[5];
    if (t < 40){
        #pragma unroll
        for (int cc=0;cc<8;++cc) kv[cc] = h2f(K[kb0 + t + 40*cc]);
    }
    #pragma unroll
    for (int j=0;j<5;++j) sv[j] = h2f(srow[t+64*j]);
    v2f acc[5];
    #pragma unroll
    for (int j=0;j<5;++j) acc[j]=(v2f){0.f,0.f};
    #pragma unroll
    for (int c0=0;c0<2;++c0){
        a3_fromregs<1>(A, t, w320, kv);
        v2f kv2[8], sv2[5];
        if (c0<1){
            long kb = kb0 + (long)HW;
            const h2* sr2 = srow + (long)HW;
            if (t < 40){
                #pragma unroll
                for (int cc=0;cc<8;++cc) kv2[cc] = h2f(K[kb + t + 40*cc]);
            }
            #pragma unroll
            for (int j=0;j<5;++j) sv2[j] = h2f(sr2[t+64*j]);
        }
        wsync();
        a2_stage<1>(A, t, w40);
        wsync();
        v2f x5[5];
        a1_toregs<1>(A, t, x5);
        #pragma unroll
        for (int j=0;j<5;++j){
            // acc += conj(s)*u  (2 packed FMAs)
            acc[j] += (v2f){sv[j].x,sv[j].x}*x5[j]
                    + (v2f){sv[j].y,-sv[j].y}*(v2f){x5[j].y,x5[j].x};
        }
        wsync();                   // a1 reads done before next a3 writes
        if (c0<1){
            #pragma unroll
            for (int cc=0;cc<8;++cc) kv[cc]=kv2[cc];
            #pragma unroll
            for (int j=0;j<5;++j) sv[j]=sv2[j];
        }
    }
    // combine halves: half1 deposits acc in its own LDS row buffer
    if (half == 1){
        #pragma unroll
        for (int j=0;j<5;++j) A[t + 64*j] = acc[j];
    }
    __syncthreads();
    if (half == 0){
        long obase = ((long)cg*NS + s)*HW + h*NDIM;
        #pragma unroll
        for (int j=0;j<5;++j){
            int idx = t + 64*j;
            part[obase+idx] = f2h(acc[j] + bufA[4+rl][idx]);
        }
    }
}

// ---------------------------------------------------------------------------
__global__ __launch_bounds__(256) void k_rhs_fin(
    const h2* __restrict__ part, const v2f* __restrict__ Iin,
    v2f* __restrict__ r, v2f* __restrict__ x, float* __restrict__ scal)
{
    __shared__ float red[256];
    int gid = blockIdx.x*blockDim.x + threadIdx.x;
    int gsz = gridDim.x*blockDim.x;
    float rs = 0.f;
    const int NV = NS*HW;
    for (int i = gid; i < NV; i += gsz){
        int w = i % NDIM; int h = (i/NDIM)%NDIM; int s = i/HW;
        v2f iv = Iin[((long)s*NDIM + sh160(h))*NDIM + sh160(w)];
        v2f rr = h2f(part[i]) + h2f(part[NV+i]) + h2f(part[2*NV+i])
               + h2f(part[3*NV+i]) + iv*RHO_;
        r[i] = rr;
        x[i] = (v2f){0.f,0.f};
        rs += rr.x*rr.x + rr.y*rr.y;
    }
    red[threadIdx.x]=rs; __syncthreads();
    for (int o=128;o>0;o>>=1){ if (threadIdx.x<o) red[threadIdx.x]+=red[threadIdx.x+o]; __syncthreads(); }
    if (threadIdx.x==0) atomicAdd(&scal[0], red[0]);
}

// ---------------------------------------------------------------------------
__global__ __launch_bounds__(256) void k_update(
    v2f* __restrict__ x, v2f* __restrict__ r,
    const v2f* __restrict__ p, const h2* __restrict__ part,
    float* __restrict__ scal, int iter)
{
    __shared__ float red[256];
    float alpha = scal[iter] / (scal[16+iter] + 1e-12f);
    int gid = blockIdx.x*blockDim.x + threadIdx.x;
    int gsz = gridDim.x*blockDim.x;
    float rs = 0.f;
    const int NV = NS*HW;
    for (int i = gid; i < NV; i += gsz){
        v2f pvv=p[i];
        v2f av = h2f(part[i]) + h2f(part[NV+i]) + h2f(part[2*NV+i])
               + h2f(part[3*NV+i]) + pvv*RHO_;
        v2f xv = x[i] + pvv*alpha;
        v2f rv = r[i] - av*alpha;
        x[i]=xv; r[i]=rv;
        rs += rv.x*rv.x + rv.y*rv.y;
    }
    red[threadIdx.x]=rs; __syncthreads();
    for (int o=128;o>0;o>>=1){ if (threadIdx.x<o) red[threadIdx.x]+=red[threadIdx.x+o]; __syncthreads(); }
    if (threadIdx.x==0) atomicAdd(&scal[iter+1], red[0]);
}

__global__ void k_final(const v2f* __restrict__ x, v2f* __restrict__ out)
{
    int gid = blockIdx.x*blockDim.x + threadIdx.x;
    int gsz = gridDim.x*blockDim.x;
    for (int i = gid; i < NS*HW; i += gsz){
        int w = i % NDIM; int h = (i/NDIM)%NDIM; int s = i/HW;
        out[i] = x[(long)s*HW + sh160(h)*NDIM + sh160(w)];
    }
}

extern "C" void kernel_launch(void* const* d_in, const int* in_sizes, int n_in,
                              void* d_out, int out_size, void* d_ws, size_t ws_size,
                              hipStream_t stream) {
    (void)in_sizes; (void)n_in; (void)out_size; (void)ws_size;
    const v2f* kin  = (const v2f*)d_in[0];
    const v2f* Iin  = (const v2f*)d_in[1];
    const v2f* csm  = (const v2f*)d_in[2];
    const float* mask = (const float*)d_in[3];

    char* w = (char*)d_ws;
    size_t off = 0;
    float* scal = (float*)(w+off);  off += 1024;
    h2* sP    = (h2*)(w+off);  off += (size_t)NC*HW*4;
    float* mscT = (float*)(w+off); off += (size_t)NS*HW*4;
    h2* K     = (h2*)(w+off);  off += (size_t)NS*NC*HW*4;
    v2f* x    = (v2f*)(w+off); off += (size_t)NS*HW*8;
    v2f* r    = (v2f*)(w+off); off += (size_t)NS*HW*8;
    v2f* pA   = (v2f*)(w+off); off += (size_t)NS*HW*8;
    v2f* pB   = (v2f*)(w+off); off += (size_t)NS*HW*8;
    h2* part  = (h2*)(w+off);  off += (size_t)4*NS*HW*4;

    k_prep<<<2048,256,0,stream>>>(kin, mask, csm, sP, mscT, K, scal);
    k_passB<<<NS*NC*20,512,0,stream>>>(K, mscT, scal, 0, 0);
    k_passC2<<<NS*80*4,512,0,stream>>>(K, sP, part);
    k_rhs_fin<<<640,256,0,stream>>>(part, Iin, r, x, scal);

    for (int it=0; it<CG_ITERS; ++it){
        v2f* pNew = (it&1)? pB : pA;
        v2f* pOld = (it&1)? pA : pB;
        k_passA<<<NS*80*4,512,0,stream>>>(r, pOld, pNew, sP, K, scal, it);
        k_passB<<<NS*NC*20,512,0,stream>>>(K, mscT, scal, it, 1);
        k_passC2<<<NS*80*4,512,0,stream>>>(K, sP, part);
        k_update<<<640,256,0,stream>>>(x, r, pNew, part, scal, it);
    }
    k_final<<<512,256,0,stream>>>(x, (v2f*)d_out);
}

// Round 15
// 1397.036 us; speedup vs baseline: 1.1100x; 1.0098x over previous
//
#include <hip/hip_runtime.h>
#include <math.h>

// ---------------------------------------------------------------------------
// SENSE CG reconstruction, B=1, S=4, C=16, H=W=320, rho=0.1, 15 CG iters.
// R6: FFT-320 = Stockham {5,8,8}; R7: packed-fp32 complex math (v2f);
// R8: K/sP in fp16; R9: passB 16-col tiles, h8v (16B/lane) global access.
// R12: row kernels 512thr/8-wave; R14: Parseval pAp in passB (1459);
// R17: passB LDS pad L=325 (1443); R18: fp16 part (1422);
// R19: passB dual-column ILP (1411). R13/R15/R16 (REVERTED).
// R20: passC2 dual-coil ILP (same proven lever as R19): each wave runs its
//     2 coils SIMULTANEOUSLY through 2 LDS buffers (a3/a2/a1_dual), shared
//     twiddles, 3 fewer wsyncs, no prefetch juggling. LDS 20.5->41 KB =
//     3 blocks/CU = 24 waves offered (vs 32) - the tradeoff that won in
//     passB. Arithmetic bit-identical.
// ---------------------------------------------------------------------------

#define NDIM 320
#define HHALF 160
#define HW (NDIM*NDIM)
#define NS 4
#define NC 16
#define RHO_ 0.1f
#define CG_ITERS 15

typedef float v2f __attribute__((ext_vector_type(2)));
typedef _Float16 h2 __attribute__((ext_vector_type(2)));
typedef _Float16 h8v __attribute__((ext_vector_type(8)));

__device__ __forceinline__ v2f h2f(h2 h){ return (v2f){(float)h.x, (float)h.y}; }
__device__ __forceinline__ h2 f2h(v2f v){ return (h2){(_Float16)v.x, (_Float16)v.y}; }

__device__ __forceinline__ void wsync(){
    __builtin_amdgcn_fence(__ATOMIC_ACQ_REL, "wavefront");
    __builtin_amdgcn_wave_barrier();
}

__device__ __forceinline__ float wred(float v){
    #pragma unroll
    for (int o=32;o>0;o>>=1) v += __shfl_down(v,o,64);
    return v;  // valid on lane 0
}

// complex mul: 2 packed FMAs
__device__ __forceinline__ v2f cmulf(v2f a, v2f b){
    return (v2f){a.x,a.x}*b + (v2f){-a.y,a.y}*(v2f){b.y,b.x};
}

template<int SIGMA>
__device__ __forceinline__ v2f cmulw(v2f a, v2f w){
    v2f wb = (SIGMA<0) ? w : (v2f){w.x, -w.y};
    return cmulf(a, wb);
}

template<int SIGMA>
__device__ __forceinline__ v2f mulj(v2f z){  // SIGMA*i*z
    return (v2f){ -(float)SIGMA*z.y, (float)SIGMA*z.x };
}

template<int SIGMA>
__device__ __forceinline__ void radix5(const v2f* u, v2f* v){
    const float C1 = 0.30901699437494742f, S1 = 0.95105651629515357f;
    const float C2 = -0.80901699437494745f, S2 = 0.58778525229247312f;
    v2f t1=u[1]+u[4], t2=u[2]+u[3], t3=u[1]-u[4], t4=u[2]-u[3];
    v[0] = u[0] + t1 + t2;
    v2f m1 = u[0] + t1*C1 + t2*C2;
    v2f m2 = u[0] + t1*C2 + t2*C1;
    v2f n1 = t3*S1 + t4*S2;
    v2f n2 = t3*S2 - t4*S1;
    v2f j1 = mulj<SIGMA>(n1), j2 = mulj<SIGMA>(n2);
    v[1]=m1+j1; v[4]=m1-j1; v[2]=m2+j2; v[3]=m2-j2;
}

template<int SIGMA>
__device__ __forceinline__ void dft8(const v2f* u, v2f* y){
    const float C = 0.70710678118654752f;
    v2f a0=u[0]+u[4], a1=u[0]-u[4];
    v2f a2=u[2]+u[6], a3=u[2]-u[6];
    v2f a4=u[1]+u[5], a5=u[1]-u[5];
    v2f a6=u[3]+u[7], a7=u[3]-u[7];
    v2f j3 = mulj<SIGMA>(a3);
    v2f E0=a0+a2, E2=a0-a2;
    v2f E1=a1+j3, E3=a1-j3;
    v2f j7 = mulj<SIGMA>(a7);
    v2f O0=a4+a6, O2=a4-a6;
    v2f O1=a5+j7, O3=a5-j7;
    v2f W1 = (O1 + mulj<SIGMA>(O1)) * C;
    v2f jO2 = mulj<SIGMA>(O2);
    v2f W3 = (mulj<SIGMA>(O3) - O3) * C;
    y[0]=E0+O0; y[4]=E0-O0;
    y[1]=E1+W1; y[5]=E1-W1;
    y[2]=E2+jO2; y[6]=E2-jO2;
    y[3]=E3+W3; y[7]=E3-W3;
}

// ---- forward Stockham {5,8,8}: natural in -> natural out -------------------
template<int SIGMA>
__device__ __forceinline__ void s1_from_regs(v2f* __restrict__ A, int t,
                                             const v2f* u5){
    v2f v[5];
    radix5<SIGMA>(u5, v);
    #pragma unroll
    for (int c=0;c<5;++c) A[5*t + c] = v[c];
}

template<int SIGMA>
__device__ __forceinline__ void s2_stage(v2f* __restrict__ A, int t, v2f w40){
    if (t < 40){
        v2f u[8];
        #pragma unroll
        for (int q=0;q<8;++q) u[q] = A[t + 40*q];
        wsync();
        v2f wc = w40;
        u[1] = cmulw<SIGMA>(u[1], wc);
        #pragma unroll
        for (int q=2;q<8;++q){ wc = cmulf(wc, w40); u[q] = cmulw<SIGMA>(u[q], wc); }
        v2f v[8];
        dft8<SIGMA>(u, v);
        int k = t % 5, jb = t / 5;
        int base = jb*40 + k;
        #pragma unroll
        for (int c=0;c<8;++c) A[base + 5*c] = v[c];
    }
}

template<int SIGMA>
__device__ __forceinline__ void s3_toregs(const v2f* __restrict__ A, int t,
                                          v2f w320, v2f* v){
    if (t < 40){
        v2f u[8];
        #pragma unroll
        for (int q=0;q<8;++q) u[q] = A[t + 40*q];
        v2f wc = w320;
        u[1] = cmulw<SIGMA>(u[1], wc);
        #pragma unroll
        for (int q=2;q<8;++q){ wc = cmulf(wc, w320); u[q] = cmulw<SIGMA>(u[q], wc); }
        dft8<SIGMA>(u, v);
    }
}

// ---- dual-chain primitives (2 independent 320-FFT chains per wave) --------
template<int SIGMA>
__device__ __forceinline__ void s1_dual(v2f* __restrict__ A0,
                                        v2f* __restrict__ A1, int t){
    v2f a[5], b[5];
    #pragma unroll
    for (int q=0;q<5;++q){ a[q] = A0[t + 64*q]; b[q] = A1[t + 64*q]; }
    wsync();
    v2f va[5], vb[5];
    radix5<SIGMA>(a, va); radix5<SIGMA>(b, vb);
    #pragma unroll
    for (int c=0;c<5;++c){ A0[5*t + c] = va[c]; A1[5*t + c] = vb[c]; }
}

template<int SIGMA>
__device__ __forceinline__ void s2_dual(v2f* __restrict__ A0,
                                        v2f* __restrict__ A1, int t, v2f w40){
    if (t < 40){
        v2f a[8], b[8];
        #pragma unroll
        for (int q=0;q<8;++q){ a[q] = A0[t + 40*q]; b[q] = A1[t + 40*q]; }
        wsync();
        v2f wc = w40;
        a[1] = cmulw<SIGMA>(a[1], wc); b[1] = cmulw<SIGMA>(b[1], wc);
        #pragma unroll
        for (int q=2;q<8;++q){
            wc = cmulf(wc, w40);
            a[q] = cmulw<SIGMA>(a[q], wc); b[q] = cmulw<SIGMA>(b[q], wc);
        }
        v2f va[8], vb[8];
        dft8<SIGMA>(a, va); dft8<SIGMA>(b, vb);
        int k = t % 5, jb = t / 5;
        int base = jb*40 + k;
        #pragma unroll
        for (int c=0;c<8;++c){ A0[base + 5*c] = va[c]; A1[base + 5*c] = vb[c]; }
    }
}

template<int SIGMA>
__device__ __forceinline__ void s3_dual(const v2f* __restrict__ A0,
                                        const v2f* __restrict__ A1, int t,
                                        v2f w320, v2f* va, v2f* vb){
    if (t < 40){
        v2f a[8], b[8];
        #pragma unroll
        for (int q=0;q<8;++q){ a[q] = A0[t + 40*q]; b[q] = A1[t + 40*q]; }
        v2f wc = w320;
        a[1] = cmulw<SIGMA>(a[1], wc); b[1] = cmulw<SIGMA>(b[1], wc);
        #pragma unroll
        for (int q=2;q<8;++q){
            wc = cmulf(wc, w320);
            a[q] = cmulw<SIGMA>(a[q], wc); b[q] = cmulw<SIGMA>(b[q], wc);
        }
        dft8<SIGMA>(a, va); dft8<SIGMA>(b, vb);
    }
}

template<int SIGMA>
__device__ __forceinline__ void a3_dual(v2f* __restrict__ A0,
                                        v2f* __restrict__ A1, int t,
                                        v2f w320, const v2f* va, const v2f* vb){
    if (t < 40){
        v2f a[8], b[8];
        dft8<SIGMA>(va, a); dft8<SIGMA>(vb, b);
        v2f wc = w320;
        a[1] = cmulw<SIGMA>(a[1], wc); b[1] = cmulw<SIGMA>(b[1], wc);
        #pragma unroll
        for (int q=2;q<8;++q){
            wc = cmulf(wc, w320);
            a[q] = cmulw<SIGMA>(a[q], wc); b[q] = cmulw<SIGMA>(b[q], wc);
        }
        #pragma unroll
        for (int q=0;q<8;++q){ A0[t + 40*q] = a[q]; A1[t + 40*q] = b[q]; }
    }
}

template<int SIGMA>
__device__ __forceinline__ void a2_dual(v2f* __restrict__ A0,
                                        v2f* __restrict__ A1, int t, v2f w40){
    if (t < 40){
        int k = t % 5, jb = t / 5;
        int base = jb*40 + k;
        v2f a[8], b[8];
        #pragma unroll
        for (int c=0;c<8;++c){ a[c] = A0[base + 5*c]; b[c] = A1[base + 5*c]; }
        wsync();
        v2f ua[8], ub[8];
        dft8<SIGMA>(a, ua); dft8<SIGMA>(b, ub);
        v2f wc = w40;
        ua[1] = cmulw<SIGMA>(ua[1], wc); ub[1] = cmulw<SIGMA>(ub[1], wc);
        #pragma unroll
        for (int q=2;q<8;++q){
            wc = cmulf(wc, w40);
            ua[q] = cmulw<SIGMA>(ua[q], wc); ub[q] = cmulw<SIGMA>(ub[q], wc);
        }
        #pragma unroll
        for (int q=0;q<8;++q){ A0[t + 40*q] = ua[q]; A1[t + 40*q] = ub[q]; }
    }
}

template<int SIGMA>
__device__ __forceinline__ void a1_dual(const v2f* __restrict__ A0,
                                        const v2f* __restrict__ A1, int t,
                                        v2f* oa, v2f* ob){
    v2f a[5], b[5];
    #pragma unroll
    for (int c=0;c<5;++c){ a[c] = A0[5*t + c]; b[c] = A1[5*t + c]; }
    radix5<SIGMA>(a, oa); radix5<SIGMA>(b, ob);
}

__device__ __forceinline__ void make_w(int t, v2f& w40, v2f& w320){
    float sn, cs;
    const float n2pi = -6.283185307179586f;
    __sincosf(n2pi*(float)(t%5)/40.f, &sn, &cs); w40  = (v2f){cs, sn};
    __sincosf(n2pi*(float)t/320.f,    &sn, &cs); w320 = (v2f){cs, sn};
}

__device__ __forceinline__ int sh160(int i){ return i < HHALF ? i + HHALF : i - HHALF; }

// ---------------------------------------------------------------------------
__global__ void k_prep(const v2f* __restrict__ kin, const float* __restrict__ mask,
                       const v2f* __restrict__ csm, h2* __restrict__ sP,
                       float* __restrict__ mscT, h2* __restrict__ K,
                       float* __restrict__ scal)
{
    int gid = blockIdx.x*blockDim.x + threadIdx.x;
    int gsz = gridDim.x*blockDim.x;
    if (gid < 64) scal[gid] = 0.f;
    for (int i = gid; i < NC*HW; i += gsz){
        int w = i % NDIM; int h = (i/NDIM) % NDIM; int c = i/HW;
        sP[i] = f2h(csm[(c*NDIM + sh160(h))*NDIM + sh160(w)]);
    }
    for (int i = gid; i < NS*HW; i += gsz){
        int h = i % NDIM; int wc = (i/NDIM)%NDIM; int s = i/HW;
        float m = mask[(s*NDIM + sh160(h))*NDIM + sh160(wc)];
        mscT[i] = m*m*(1.0f/102400.0f);
    }
    for (int i = gid; i < NS*NC*HW; i += gsz){
        int w = i % NDIM; int h = (i/NDIM)%NDIM; int sc = i/HW;
        int s = sc >> 4;
        int hs = sh160(h), ws = sh160(w);
        float m = mask[(s*NDIM + hs)*NDIM + ws];
        v2f kv = kin[((long)sc*NDIM + hs)*NDIM + ws];
        float f = m*(1.0f/320.0f);
        K[i] = f2h(kv * f);
    }
}

// ---------------------------------------------------------------------------
// PassA (R12): p = r + beta*p fused; K[s,c,h,:] = rowFFT(s'_c .* p).
// grid = S*80*4 ; 512 thr = 8 waves: waves 0-3 rows x coils {c,c+1},
// waves 4-7 same rows x coils {c+2,c+3}. pv staged via LDS (half0 loads).
__global__ __launch_bounds__(512) void k_passA(
    const v2f* __restrict__ rv_, const v2f* __restrict__ pOld,
    v2f* __restrict__ pNew, const h2* __restrict__ sP,
    h2* __restrict__ K, float* __restrict__ scal, int iter)
{
    int bid = blockIdx.x;
    int cg = bid & 3;
    int hg = (bid>>2) % 80;
    int s  = bid / (4*80);
    int tid = threadIdx.x;
    int wv = tid>>6; int rl = wv&3; int half = wv>>2; int t = tid&63;
    int h = hg*4 + rl;
    __shared__ v2f bufA[8][NDIM];
    __shared__ v2f pbuf[4][NDIM];
    v2f* A = &bufA[wv][0];
    v2f w40, w320; make_w(t, w40, w320);
    long base = (long)s*HW + h*NDIM;
    v2f pv[5];
    if (half == 0){
        float beta = 0.f;
        if (iter > 0) beta = scal[iter] / (scal[iter-1] + 1e-12f);
        #pragma unroll
        for (int j=0;j<5;++j){
            int idx = t + 64*j;
            v2f rr = rv_[base+idx];
            if (iter > 0){
                v2f pp = pOld[base+idx];
                pv[j] = rr + pp*beta;
            } else pv[j] = rr;
            pbuf[rl][idx] = pv[j];
        }
        if (cg == 0){
            float d = 0.f;
            #pragma unroll
            for (int j=0;j<5;++j){
                pNew[base + t + 64*j] = pv[j];
                d += pv[j].x*pv[j].x + pv[j].y*pv[j].y;
            }
            float wd = wred(d);
            if (t==0) atomicAdd(&scal[16+iter], RHO_*wd);
        }
    }
    __syncthreads();
    if (half == 1){
        #pragma unroll
        for (int j=0;j<5;++j) pv[j] = pbuf[rl][t + 64*j];
    }
    int c = cg*4 + half*2;
    const h2* srow = sP + (long)c*HW + h*NDIM;
    v2f sv[5];
    #pragma unroll
    for (int j=0;j<5;++j) sv[j] = h2f(srow[t+64*j]);
    #pragma unroll
    for (int c0=0;c0<2;++c0){
        v2f u5[5];
        #pragma unroll
        for (int j=0;j<5;++j) u5[j] = cmulf(sv[j], pv[j]);
        v2f sv2[5];
        if (c0<1){
            const h2* sr2 = srow + (long)HW;
            #pragma unroll
            for (int j=0;j<5;++j) sv2[j] = h2f(sr2[t+64*j]);
        }
        wsync();                                   // prior-iter S3 reads done
        s1_from_regs<-1>(A, t, u5);
        wsync();
        s2_stage<-1>(A, t, w40);
        wsync();
        v2f v8[8];
        s3_toregs<-1>(A, t, w320, v8);
        long kb = ((long)(s*NC + c + c0))*HW + h*NDIM;
        if (t < 40){
            #pragma unroll
            for (int cc=0;cc<8;++cc) K[kb + t + 40*cc] = f2h(v8[cc]);
        }
        if (c0<1){
            #pragma unroll
            for (int j=0;j<5;++j) sv[j]=sv2[j];
        }
    }
}

// ---------------------------------------------------------------------------
// PassB (R9 tiles + Parseval pAp + R17 pad + R19 dual-column): 16-column LDS
// tile; h8v (16B/lane); 512 thr = 8 waves, wave wv handles cols 2wv,2wv+1.
__global__ __launch_bounds__(512) void k_passB(h2* __restrict__ K,
    const float* __restrict__ mscT, float* __restrict__ scal, int iter,
    int doMask)
{
    constexpr int L = 325;
    int bid = blockIdx.x;
    int wt = bid % 20;
    int sc = bid / 20;
    int s = sc >> 4;
    int tid = threadIdx.x;
    int wv = tid >> 6;           // 0..7
    int t = tid & 63;
    int w0 = wt*16;
    __shared__ v2f bufA[16][L];
    __shared__ float redP[8];
    v2f w40, w320; make_w(t, w40, w320);
    float mvA[8], mvB[8];
    if (doMask && t < 40){
        const float* mA = mscT + (long)s*HW + (long)(w0+2*wv)*NDIM;
        const float* mB = mA + NDIM;
        #pragma unroll
        for (int cc=0;cc<8;++cc){ mvA[cc] = mA[t+40*cc]; mvB[cc] = mB[t+40*cc]; }
    }
    long gb = (long)sc*HW + w0;
    for (int i = tid; i < NDIM*4; i += 512){
        int row = i >> 2, ch = i & 3;
        h8v val = *(const h8v*)&K[gb + (long)row*NDIM + ch*4];
        #pragma unroll
        for (int k=0;k<4;++k)
            bufA[ch*4+k][row] = (v2f){(float)val[2*k], (float)val[2*k+1]};
    }
    __syncthreads();
    v2f* A0 = &bufA[2*wv][0];
    v2f* A1 = &bufA[2*wv+1][0];
    if (doMask){
        s1_dual<-1>(A0, A1, t);
        wsync();
        s2_dual<-1>(A0, A1, t, w40);
        wsync();
        v2f v8A[8], v8B[8];
        s3_dual<-1>(A0, A1, t, w320, v8A, v8B);
        float pap = 0.f;
        if (t < 40){
            #pragma unroll
            for (int cc=0;cc<8;++cc){
                float mA = mvA[cc], mB = mvB[cc];
                pap += mA*(v8A[cc].x*v8A[cc].x + v8A[cc].y*v8A[cc].y)
                     + mB*(v8B[cc].x*v8B[cc].x + v8B[cc].y*v8B[cc].y);
                v8A[cc] = v8A[cc]*mA;
                v8B[cc] = v8B[cc]*mB;
            }
        }
        {
            float wp = wred(pap);
            if (t==0) redP[wv] = wp;
        }
        wsync();
        a3_dual<1>(A0, A1, t, w320, v8A, v8B);
        wsync();
        a2_dual<1>(A0, A1, t, w40);
        wsync();
        v2f x5A[5], x5B[5];
        a1_dual<1>(A0, A1, t, x5A, x5B);
        wsync();
        #pragma unroll
        for (int q=0;q<5;++q){ A0[t + 64*q] = x5A[q]; A1[t + 64*q] = x5B[q]; }
    } else {
        s1_dual<1>(A0, A1, t);
        wsync();
        s2_dual<1>(A0, A1, t, w40);
        wsync();
        v2f v8A[8], v8B[8];
        s3_dual<1>(A0, A1, t, w320, v8A, v8B);
        wsync();
        if (t < 40){
            #pragma unroll
            for (int cc=0;cc<8;++cc){ A0[t + 40*cc] = v8A[cc]; A1[t + 40*cc] = v8B[cc]; }
        }
    }
    __syncthreads();
    for (int i = tid; i < NDIM*4; i += 512){
        int row = i >> 2, ch = i & 3;
        h8v val;
        #pragma unroll
        for (int k=0;k<4;++k){
            v2f u = bufA[ch*4+k][row];
            val[2*k] = (_Float16)u.x; val[2*k+1] = (_Float16)u.y;
        }
        *(h8v*)&K[gb + (long)row*NDIM + ch*4] = val;
    }
    if (doMask && tid==0){
        float sum = 0.f;
        #pragma unroll
        for (int k=0;k<8;++k) sum += redP[k];
        atomicAdd(&scal[16+iter], sum);
    }
}

// ---------------------------------------------------------------------------
// PassC2 (R20 dual-coil): row inverse; wave wv handles coils c, c+1
// SIMULTANEOUSLY through 2 LDS buffers. Halves combined via LDS;
// conj(s')-combine into part[cg] (fp16). grid = S*80*4 ; 512 thr = 8 waves.
// LDS 16*320*8 = 41 KB -> 3 blocks/CU.
__global__ __launch_bounds__(512) void k_passC2(
    const h2* __restrict__ K, const h2* __restrict__ sP,
    h2* __restrict__ part)
{
    int bid = blockIdx.x;
    int cg = bid & 3;
    int hg = (bid>>2) % 80;
    int s  = bid / (4*80);
    int tid = threadIdx.x;
    int wv = tid>>6; int rl = wv&3; int half = wv>>2; int t = tid&63;
    int h = hg*4 + rl;
    __shared__ v2f bufA[16][NDIM];
    v2f* A0 = &bufA[2*wv][0];
    v2f* A1 = &bufA[2*wv+1][0];
    v2f w40, w320; make_w(t, w40, w320);
    int c = cg*4 + half*2;
    long kb0 = ((long)(s*NC + c))*HW + h*NDIM;
    const h2* srow = sP + (long)c*HW + h*NDIM;
    v2f kvA[8], kvB[8], svA[5], svB[5];
    if (t < 40){
        #pragma unroll
        for (int cc=0;cc<8;++cc){
            kvA[cc] = h2f(K[kb0 + t + 40*cc]);
            kvB[cc] = h2f(K[kb0 + (long)HW + t + 40*cc]);
        }
    }
    #pragma unroll
    for (int j=0;j<5;++j){
        svA[j] = h2f(srow[t+64*j]);
        svB[j] = h2f(srow[(long)HW + t+64*j]);
    }
    a3_dual<1>(A0, A1, t, w320, kvA, kvB);
    wsync();
    a2_dual<1>(A0, A1, t, w40);
    wsync();
    v2f x5A[5], x5B[5];
    a1_dual<1>(A0, A1, t, x5A, x5B);
    v2f acc[5];
    #pragma unroll
    for (int j=0;j<5;++j){
        // acc = conj(sA)*uA + conj(sB)*uB  (same order as sequential version)
        acc[j] = (v2f){svA[j].x,svA[j].x}*x5A[j]
               + (v2f){svA[j].y,-svA[j].y}*(v2f){x5A[j].y,x5A[j].x};
        acc[j] += (v2f){svB[j].x,svB[j].x}*x5B[j]
                + (v2f){svB[j].y,-svB[j].y}*(v2f){x5B[j].y,x5B[j].x};
    }
    // combine halves: half1 deposits acc into its A0 buffer (bufA[8..15])
    wsync();                       // a1 reads done before overwrite
    if (half == 1){
        #pragma unroll
        for (int j=0;j<5;++j) A0[t + 64*j] = acc[j];
    }
    __syncthreads();
    if (half == 0){
        long obase = ((long)cg*NS + s)*HW + h*NDIM;
        #pragma unroll
        for (int j=0;j<5;++j){
            int idx = t + 64*j;
            part[obase+idx] = f2h(acc[j] + bufA[2*(wv+4)][idx]);
        }
    }
}

// ---------------------------------------------------------------------------
__global__ __launch_bounds__(256) void k_rhs_fin(
    const h2* __restrict__ part, const v2f* __restrict__ Iin,
    v2f* __restrict__ r, v2f* __restrict__ x, float* __restrict__ scal)
{
    __shared__ float red[256];
    int gid = blockIdx.x*blockDim.x + threadIdx.x;
    int gsz = gridDim.x*blockDim.x;
    float rs = 0.f;
    const int NV = NS*HW;
    for (int i = gid; i < NV; i += gsz){
        int w = i % NDIM; int h = (i/NDIM)%NDIM; int s = i/HW;
        v2f iv = Iin[((long)s*NDIM + sh160(h))*NDIM + sh160(w)];
        v2f rr = h2f(part[i]) + h2f(part[NV+i]) + h2f(part[2*NV+i])
               + h2f(part[3*NV+i]) + iv*RHO_;
        r[i] = rr;
        x[i] = (v2f){0.f,0.f};
        rs += rr.x*rr.x + rr.y*rr.y;
    }
    red[threadIdx.x]=rs; __syncthreads();
    for (int o=128;o>0;o>>=1){ if (threadIdx.x<o) red[threadIdx.x]+=red[threadIdx.x+o]; __syncthreads(); }
    if (threadIdx.x==0) atomicAdd(&scal[0], red[0]);
}

// ---------------------------------------------------------------------------
__global__ __launch_bounds__(256) void k_update(
    v2f* __restrict__ x, v2f* __restrict__ r,
    const v2f* __restrict__ p, const h2* __restrict__ part,
    float* __restrict__ scal, int iter)
{
    __shared__ float red[256];
    float alpha = scal[iter] / (scal[16+iter] + 1e-12f);
    int gid = blockIdx.x*blockDim.x + threadIdx.x;
    int gsz = gridDim.x*blockDim.x;
    float rs = 0.f;
    const int NV = NS*HW;
    for (int i = gid; i < NV; i += gsz){
        v2f pvv=p[i];
        v2f av = h2f(part[i]) + h2f(part[NV+i]) + h2f(part[2*NV+i])
               + h2f(part[3*NV+i]) + pvv*RHO_;
        v2f xv = x[i] + pvv*alpha;
        v2f rv = r[i] - av*alpha;
        x[i]=xv; r[i]=rv;
        rs += rv.x*rv.x + rv.y*rv.y;
    }
    red[threadIdx.x]=rs; __syncthreads();
    for (int o=128;o>0;o>>=1){ if (threadIdx.x<o) red[threadIdx.x]+=red[threadIdx.x+o]; __syncthreads(); }
    if (threadIdx.x==0) atomicAdd(&scal[iter+1], red[0]);
}

__global__ void k_final(const v2f* __restrict__ x, v2f* __restrict__ out)
{
    int gid = blockIdx.x*blockDim.x + threadIdx.x;
    int gsz = gridDim.x*blockDim.x;
    for (int i = gid; i < NS*HW; i += gsz){
        int w = i % NDIM; int h = (i/NDIM)%NDIM; int s = i/HW;
        out[i] = x[(long)s*HW + sh160(h)*NDIM + sh160(w)];
    }
}

extern "C" void kernel_launch(void* const* d_in, const int* in_sizes, int n_in,
                              void* d_out, int out_size, void* d_ws, size_t ws_size,
                              hipStream_t stream) {
    (void)in_sizes; (void)n_in; (void)out_size; (void)ws_size;
    const v2f* kin  = (const v2f*)d_in[0];
    const v2f* Iin  = (const v2f*)d_in[1];
    const v2f* csm  = (const v2f*)d_in[2];
    const float* mask = (const float*)d_in[3];

    char* w = (char*)d_ws;
    size_t off = 0;
    float* scal = (float*)(w+off);  off += 1024;
    h2* sP    = (h2*)(w+off);  off += (size_t)NC*HW*4;
    float* mscT = (float*)(w+off); off += (size_t)NS*HW*4;
    h2* K     = (h2*)(w+off);  off += (size_t)NS*NC*HW*4;
    v2f* x    = (v2f*)(w+off); off += (size_t)NS*HW*8;
    v2f* r    = (v2f*)(w+off); off += (size_t)NS*HW*8;
    v2f* pA   = (v2f*)(w+off); off += (size_t)NS*HW*8;
    v2f* pB   = (v2f*)(w+off); off += (size_t)NS*HW*8;
    h2* part  = (h2*)(w+off);  off += (size_t)4*NS*HW*4;

    k_prep<<<2048,256,0,stream>>>(kin, mask, csm, sP, mscT, K, scal);
    k_passB<<<NS*NC*20,512,0,stream>>>(K, mscT, scal, 0, 0);
    k_passC2<<<NS*80*4,512,0,stream>>>(K, sP, part);
    k_rhs_fin<<<640,256,0,stream>>>(part, Iin, r, x, scal);

    for (int it=0; it<CG_ITERS; ++it){
        v2f* pNew = (it&1)? pB : pA;
        v2f* pOld = (it&1)? pA : pB;
        k_passA<<<NS*80*4,512,0,stream>>>(r, pOld, pNew, sP, K, scal, it);
        k_passB<<<NS*NC*20,512,0,stream>>>(K, mscT, scal, it, 1);
        k_passC2<<<NS*80*4,512,0,stream>>>(K, sP, part);
        k_update<<<640,256,0,stream>>>(x, r, pNew, part, scal, it);
    }
    k_final<<<512,256,0,stream>>>(x, (v2f*)d_out);
}